// Round 1
// baseline (316.343 us; speedup 1.0000x reference)
//
#include <hip/hip_runtime.h>

#define L_SEQ 4096
#define DMODEL 768
#define NH 12
#define DK 64

typedef __bf16 bf16;
typedef __bf16 bf16x8 __attribute__((ext_vector_type(8)));
typedef __bf16 bf16x4 __attribute__((ext_vector_type(4)));
typedef float f32x4 __attribute__((ext_vector_type(4)));

// -------------------- Kernel A: fused Q/K projection --------------------
// Y = X @ W (+bias), W in {w_q, w_k}.  Q additionally scaled by 1/8 (softmax scale).
// Output layout: [h][L][64] bf16 (head-major, row-major within head).
__global__ __launch_bounds__(256) void qk_proj_kernel(
    const float* __restrict__ x, const float* __restrict__ w_q,
    const float* __restrict__ b_q, const float* __restrict__ w_k,
    const float* __restrict__ b_k, bf16* __restrict__ qbuf, bf16* __restrict__ kbuf)
{
    __shared__ bf16 As[128][40];   // X tile [m][k], pad->stride 40 (80B, 16B-aligned)
    __shared__ bf16 Bts[64][40];   // W^T tile [n][k]
    const int bn = blockIdx.x % 24;     // 24 tiles of 64 over N=1536
    const int bm = blockIdx.x / 24;     // 32 tiles of 128 over M=4096
    const int m0 = bm * 128;
    const int gn0 = bn * 64;
    const int sel = gn0 / DMODEL;       // 0=Q, 1=K
    const int c0 = gn0 % DMODEL;
    const float* W = sel ? w_k : w_q;
    const float* bias = sel ? b_k : b_q;
    bf16* dst = sel ? kbuf : qbuf;
    const float scale = sel ? 1.0f : 0.125f;

    const int t = threadIdx.x;
    const int w = t >> 6, l = t & 63;
    const int lg = l >> 4, lr = l & 15;

    f32x4 acc[2][4];
    #pragma unroll
    for (int i = 0; i < 2; i++)
        #pragma unroll
        for (int j = 0; j < 4; j++) acc[i][j] = (f32x4){0.f, 0.f, 0.f, 0.f};

    for (int kk = 0; kk < DMODEL; kk += 32) {
        // stage A: 128x32 fp32 -> bf16, coalesced float4
        #pragma unroll
        for (int p = 0; p < 4; ++p) {
            int id = t + p * 256;
            int row = id >> 3, c4 = id & 7;
            const float4 v = *(const float4*)(x + (size_t)(m0 + row) * DMODEL + kk + c4 * 4);
            bf16x4 b; b[0] = (bf16)v.x; b[1] = (bf16)v.y; b[2] = (bf16)v.z; b[3] = (bf16)v.w;
            *(bf16x4*)&As[row][c4 * 4] = b;
        }
        // stage B^T: 64n x 32k, read coalesced along n
        #pragma unroll
        for (int p = 0; p < 8; ++p) {
            int id = t + p * 256;
            int n = id & 63, kr = id >> 6;
            Bts[n][kr] = (bf16)W[(size_t)(kk + kr) * DMODEL + c0 + n];
        }
        __syncthreads();
        bf16x8 a[2], bfr[4];
        #pragma unroll
        for (int i = 0; i < 2; i++) a[i] = *(const bf16x8*)&As[w * 32 + i * 16 + lr][lg * 8];
        #pragma unroll
        for (int j = 0; j < 4; j++) bfr[j] = *(const bf16x8*)&Bts[j * 16 + lr][lg * 8];
        #pragma unroll
        for (int i = 0; i < 2; i++)
            #pragma unroll
            for (int j = 0; j < 4; j++)
                acc[i][j] = __builtin_amdgcn_mfma_f32_16x16x32_bf16(a[i], bfr[j], acc[i][j], 0, 0, 0);
        __syncthreads();
    }
    // epilogue: bias + scale, write head-major bf16
    #pragma unroll
    for (int i = 0; i < 2; i++) {
        #pragma unroll
        for (int j = 0; j < 4; j++) {
            int c = c0 + j * 16 + lr;            // col within matrix [0,768)
            int h = c >> 6, d = c & 63;
            float bb = bias[c];
            #pragma unroll
            for (int r = 0; r < 4; r++) {
                int m = m0 + w * 32 + i * 16 + lg * 4 + r;
                float v = (acc[i][j][r] + bb) * scale;
                dst[((size_t)h * L_SEQ + m) * DK + d] = (bf16)v;
            }
        }
    }
}

// -------------------- Kernel B: V projection, transposed output --------------------
// vt[c][m] = sum_k Wv[k][c] * X[m][k] + b_v[c]   (c = h*64+d), layout [768][4096] bf16.
__global__ __launch_bounds__(256) void v_proj_kernel(
    const float* __restrict__ x, const float* __restrict__ w_v,
    const float* __restrict__ b_v, bf16* __restrict__ vt)
{
    __shared__ bf16 Wt[64][40];    // Wv^T tile [c'][k]
    __shared__ bf16 Xs[128][40];   // X tile [m'][k]
    const int bc = blockIdx.x % 12;   // c tiles (64)
    const int bmm = blockIdx.x / 12;  // m tiles (128)
    const int c0 = bc * 64;
    const int mm0 = bmm * 128;
    const int t = threadIdx.x;
    const int w = t >> 6, l = t & 63;
    const int lg = l >> 4, lr = l & 15;

    f32x4 acc[8];
    #pragma unroll
    for (int j = 0; j < 8; j++) acc[j] = (f32x4){0.f, 0.f, 0.f, 0.f};

    for (int kk = 0; kk < DMODEL; kk += 32) {
        #pragma unroll
        for (int p = 0; p < 4; ++p) {
            int id = t + p * 256;
            int row = id >> 3, c4 = id & 7;
            const float4 v = *(const float4*)(x + (size_t)(mm0 + row) * DMODEL + kk + c4 * 4);
            bf16x4 b; b[0] = (bf16)v.x; b[1] = (bf16)v.y; b[2] = (bf16)v.z; b[3] = (bf16)v.w;
            *(bf16x4*)&Xs[row][c4 * 4] = b;
        }
        #pragma unroll
        for (int p = 0; p < 8; ++p) {
            int id = t + p * 256;
            int n = id & 63, kr = id >> 6;
            Wt[n][kr] = (bf16)w_v[(size_t)(kk + kr) * DMODEL + c0 + n];
        }
        __syncthreads();
        bf16x8 a = *(const bf16x8*)&Wt[w * 16 + lr][lg * 8];
        #pragma unroll
        for (int j = 0; j < 8; j++) {
            bf16x8 b = *(const bf16x8*)&Xs[j * 16 + lr][lg * 8];
            acc[j] = __builtin_amdgcn_mfma_f32_16x16x32_bf16(a, b, acc[j], 0, 0, 0);
        }
        __syncthreads();
    }
    #pragma unroll
    for (int j = 0; j < 8; j++) {
        int m = mm0 + j * 16 + lr;
        #pragma unroll
        for (int r = 0; r < 4; r++) {
            int c = c0 + w * 16 + lg * 4 + r;
            float v = acc[j][r] + b_v[c];
            vt[(size_t)c * L_SEQ + m] = (bf16)v;
        }
    }
}

// -------------------- Kernel C: causal flash attention --------------------
// Per block: 1 head, 64 q-rows; 4 waves x 16 rows. Q pre-scaled by 1/8.
__global__ __launch_bounds__(256) void attn_kernel(
    const bf16* __restrict__ qbuf, const bf16* __restrict__ kbuf,
    const bf16* __restrict__ vt, bf16* __restrict__ obuf)
{
    __shared__ bf16 Ks[64][72];      // K tile [kv'][d], stride 72 (144B)
    __shared__ bf16 Vs[64][72];      // V^T tile [d][kv']
    __shared__ bf16 Ps[4][16][72];   // per-wave P tile [q'][kv']
    const int h = blockIdx.x >> 6;
    const int qt = blockIdx.x & 63;
    const int q0 = qt * 64;
    const int t = threadIdx.x;
    const int w = t >> 6, l = t & 63;
    const int lg = l >> 4, lr = l & 15;

    // Q fragments in registers (A-operand, rows = wave's 16 q-rows)
    bf16x8 qa[2];
    const size_t qrow = (size_t)h * L_SEQ + q0 + w * 16 + lr;
    qa[0] = *(const bf16x8*)(qbuf + qrow * DK + 0  + lg * 8);
    qa[1] = *(const bf16x8*)(qbuf + qrow * DK + 32 + lg * 8);

    f32x4 acc[4];
    #pragma unroll
    for (int j = 0; j < 4; j++) acc[j] = (f32x4){0.f, 0.f, 0.f, 0.f};
    float run_m[4], run_s[4];
    #pragma unroll
    for (int r = 0; r < 4; r++) { run_m[r] = -1e30f; run_s[r] = 0.0f; }

    for (int kv0 = 0; kv0 <= q0; kv0 += 64) {
        // stage K and V^T tiles (16B chunks, coalesced)
        #pragma unroll
        for (int p = 0; p < 2; ++p) {
            int id = t + p * 256;
            int row = id >> 3, ch = id & 7;
            bf16x8 k8 = *(const bf16x8*)(kbuf + ((size_t)h * L_SEQ + kv0 + row) * DK + ch * 8);
            *(bf16x8*)&Ks[row][ch * 8] = k8;
            bf16x8 v8 = *(const bf16x8*)(vt + ((size_t)h * DK + row) * L_SEQ + kv0 + ch * 8);
            *(bf16x8*)&Vs[row][ch * 8] = v8;
        }
        __syncthreads();

        // S = Q K^T  (16x64 per wave)
        f32x4 s[4];
        #pragma unroll
        for (int j = 0; j < 4; j++) s[j] = (f32x4){0.f, 0.f, 0.f, 0.f};
        #pragma unroll
        for (int dh = 0; dh < 2; ++dh)
            #pragma unroll
            for (int j = 0; j < 4; j++) {
                bf16x8 kb = *(const bf16x8*)&Ks[j * 16 + lr][dh * 32 + lg * 8];
                s[j] = __builtin_amdgcn_mfma_f32_16x16x32_bf16(qa[dh], kb, s[j], 0, 0, 0);
            }
        // causal mask on diagonal tile
        if (kv0 == q0) {
            #pragma unroll
            for (int j = 0; j < 4; j++) {
                int kvcol = j * 16 + lr;
                #pragma unroll
                for (int r = 0; r < 4; r++) {
                    int qrow_l = w * 16 + lg * 4 + r;
                    if (kvcol > qrow_l) s[j][r] = -1e30f;
                }
            }
        }
        // online softmax (rows spread over 16-lane groups)
        float sc[4];
        #pragma unroll
        for (int r = 0; r < 4; r++) {
            float m = fmaxf(fmaxf(s[0][r], s[1][r]), fmaxf(s[2][r], s[3][r]));
            m = fmaxf(m, __shfl_xor(m, 1));
            m = fmaxf(m, __shfl_xor(m, 2));
            m = fmaxf(m, __shfl_xor(m, 4));
            m = fmaxf(m, __shfl_xor(m, 8));
            float nm = fmaxf(run_m[r], m);
            sc[r] = __expf(run_m[r] - nm);
            run_m[r] = nm;
            float psum = 0.0f;
            #pragma unroll
            for (int j = 0; j < 4; j++) {
                float pv = __expf(s[j][r] - nm);
                s[j][r] = pv;
                psum += pv;
            }
            psum += __shfl_xor(psum, 1);
            psum += __shfl_xor(psum, 2);
            psum += __shfl_xor(psum, 4);
            psum += __shfl_xor(psum, 8);
            run_s[r] = run_s[r] * sc[r] + psum;
        }
        // rescale O accumulators
        #pragma unroll
        for (int j = 0; j < 4; j++)
            #pragma unroll
            for (int r = 0; r < 4; r++) acc[j][r] *= sc[r];
        // P -> LDS (bf16), per-wave private region (wave-synchronous, no barrier needed)
        #pragma unroll
        for (int j = 0; j < 4; j++)
            #pragma unroll
            for (int r = 0; r < 4; r++)
                Ps[w][lg * 4 + r][j * 16 + lr] = (bf16)s[j][r];
        // PV: O += P V
        #pragma unroll
        for (int kh = 0; kh < 2; ++kh) {
            bf16x8 pa = *(const bf16x8*)&Ps[w][lr][kh * 32 + lg * 8];
            #pragma unroll
            for (int j = 0; j < 4; j++) {
                bf16x8 vb = *(const bf16x8*)&Vs[j * 16 + lr][kh * 32 + lg * 8];
                acc[j] = __builtin_amdgcn_mfma_f32_16x16x32_bf16(pa, vb, acc[j], 0, 0, 0);
            }
        }
        __syncthreads();
    }
    // normalize + write concat-head layout [L][768] bf16
    #pragma unroll
    for (int j = 0; j < 4; j++) {
        int dcol = j * 16 + lr;
        #pragma unroll
        for (int r = 0; r < 4; r++) {
            int m = q0 + w * 16 + lg * 4 + r;
            float v = acc[j][r] / run_s[r];
            obuf[(size_t)m * DMODEL + h * DK + dcol] = (bf16)v;
        }
    }
}

// -------------------- Kernel D: output projection (fp32 out) --------------------
__global__ __launch_bounds__(256) void out_proj_kernel(
    const bf16* __restrict__ obuf, const float* __restrict__ w_o,
    const float* __restrict__ b_o, float* __restrict__ out)
{
    __shared__ bf16 As[128][40];
    __shared__ bf16 Bts[64][40];
    const int bn = blockIdx.x % 12;
    const int bm = blockIdx.x / 12;
    const int m0 = bm * 128, c0 = bn * 64;
    const int t = threadIdx.x;
    const int w = t >> 6, l = t & 63, lg = l >> 4, lr = l & 15;

    f32x4 acc[2][4];
    #pragma unroll
    for (int i = 0; i < 2; i++)
        #pragma unroll
        for (int j = 0; j < 4; j++) acc[i][j] = (f32x4){0.f, 0.f, 0.f, 0.f};

    for (int kk = 0; kk < DMODEL; kk += 32) {
        #pragma unroll
        for (int p = 0; p < 2; ++p) {
            int id = t + p * 256;
            int row = id >> 2, ch = id & 3;
            bf16x8 v8 = *(const bf16x8*)(obuf + (size_t)(m0 + row) * DMODEL + kk + ch * 8);
            *(bf16x8*)&As[row][ch * 8] = v8;
        }
        #pragma unroll
        for (int p = 0; p < 8; ++p) {
            int id = t + p * 256;
            int n = id & 63, kr = id >> 6;
            Bts[n][kr] = (bf16)w_o[(size_t)(kk + kr) * DMODEL + c0 + n];
        }
        __syncthreads();
        bf16x8 a[2], bfr[4];
        #pragma unroll
        for (int i = 0; i < 2; i++) a[i] = *(const bf16x8*)&As[w * 32 + i * 16 + lr][lg * 8];
        #pragma unroll
        for (int j = 0; j < 4; j++) bfr[j] = *(const bf16x8*)&Bts[j * 16 + lr][lg * 8];
        #pragma unroll
        for (int i = 0; i < 2; i++)
            #pragma unroll
            for (int j = 0; j < 4; j++)
                acc[i][j] = __builtin_amdgcn_mfma_f32_16x16x32_bf16(a[i], bfr[j], acc[i][j], 0, 0, 0);
        __syncthreads();
    }
    #pragma unroll
    for (int i = 0; i < 2; i++) {
        #pragma unroll
        for (int j = 0; j < 4; j++) {
            int c = c0 + j * 16 + lr;
            float bb = b_o[c];
            #pragma unroll
            for (int r = 0; r < 4; r++) {
                int m = m0 + w * 32 + i * 16 + lg * 4 + r;
                out[(size_t)m * DMODEL + c] = acc[i][j][r] + bb;
            }
        }
    }
}

extern "C" void kernel_launch(void* const* d_in, const int* in_sizes, int n_in,
                              void* d_out, int out_size, void* d_ws, size_t ws_size,
                              hipStream_t stream) {
    const float* x   = (const float*)d_in[0];
    const float* w_q = (const float*)d_in[1];
    const float* b_q = (const float*)d_in[2];
    const float* w_k = (const float*)d_in[3];
    const float* b_k = (const float*)d_in[4];
    const float* w_v = (const float*)d_in[5];
    const float* b_v = (const float*)d_in[6];
    const float* w_o = (const float*)d_in[7];
    const float* b_o = (const float*)d_in[8];
    float* out = (float*)d_out;

    char* ws = (char*)d_ws;
    const size_t SZ = (size_t)NH * L_SEQ * DK * sizeof(bf16);  // 6,291,456 B each
    bf16* qbuf = (bf16*)(ws);
    bf16* kbuf = (bf16*)(ws + SZ);
    bf16* vt   = (bf16*)(ws + 2 * SZ);
    bf16* obuf = (bf16*)(ws + 3 * SZ);

    qk_proj_kernel<<<dim3(768), dim3(256), 0, stream>>>(x, w_q, b_q, w_k, b_k, qbuf, kbuf);
    v_proj_kernel<<<dim3(384), dim3(256), 0, stream>>>(x, w_v, b_v, vt);
    attn_kernel<<<dim3(768), dim3(256), 0, stream>>>(qbuf, kbuf, vt, obuf);
    out_proj_kernel<<<dim3(384), dim3(256), 0, stream>>>(obuf, w_o, b_o, out);
}

// Round 4
// 168.911 us; speedup vs baseline: 1.8728x; 1.8728x over previous
//
#include <hip/hip_runtime.h>

#define L_SEQ 4096
#define DMODEL 768
#define NH 12
#define DK 64

typedef __bf16 bf16;
typedef __bf16 bf16x8 __attribute__((ext_vector_type(8)));
typedef __bf16 bf16x4 __attribute__((ext_vector_type(4)));
typedef float f32x4 __attribute__((ext_vector_type(4)));

#define QSCALE 0.1803368801111204f  /* 0.125 * log2(e): exp2 domain */

// -------------------- Kernel A: fused Q/K/V projections --------------------
// bid < 768: Q/K path (128x64 tiles over [4096,1536]); bid >= 768: V^T path.
__global__ __launch_bounds__(256) void proj_kernel(
    const float* __restrict__ x,
    const float* __restrict__ w_q, const float* __restrict__ b_q,
    const float* __restrict__ w_k, const float* __restrict__ b_k,
    const float* __restrict__ w_v, const float* __restrict__ b_v,
    bf16* __restrict__ qbuf, bf16* __restrict__ kbuf, bf16* __restrict__ vt)
{
    __shared__ bf16 As[128][40];
    __shared__ bf16 Bs[64][40];
    const int t = threadIdx.x;
    const int w = t >> 6, l = t & 63;
    const int lg = l >> 4, lr = l & 15;

    if (blockIdx.x < 768) {
        // ---- Q/K path ----
        const int bn = blockIdx.x % 24;
        const int bm = blockIdx.x / 24;
        const int m0 = bm * 128;
        const int gn0 = bn * 64;
        const int sel = gn0 / DMODEL;        // 0=Q, 1=K
        const int c0 = gn0 % DMODEL;
        const float* W = sel ? w_k : w_q;
        const float* bias = sel ? b_k : b_q;
        bf16* dst = sel ? kbuf : qbuf;
        const float scale = sel ? 1.0f : QSCALE;

        f32x4 acc[2][4];
        #pragma unroll
        for (int i = 0; i < 2; i++)
            #pragma unroll
            for (int j = 0; j < 4; j++) acc[i][j] = (f32x4){0.f, 0.f, 0.f, 0.f};

        for (int kk = 0; kk < DMODEL; kk += 32) {
            #pragma unroll
            for (int p = 0; p < 4; ++p) {
                int id = t + p * 256;
                int row = id >> 3, c4 = id & 7;
                const float4 v = *(const float4*)(x + (size_t)(m0 + row) * DMODEL + kk + c4 * 4);
                bf16x4 b; b[0] = (bf16)v.x; b[1] = (bf16)v.y; b[2] = (bf16)v.z; b[3] = (bf16)v.w;
                *(bf16x4*)&As[row][c4 * 4] = b;
            }
            #pragma unroll
            for (int p = 0; p < 8; ++p) {
                int id = t + p * 256;
                int n = id & 63, kr = id >> 6;
                Bs[n][kr] = (bf16)W[(size_t)(kk + kr) * DMODEL + c0 + n];
            }
            __syncthreads();
            bf16x8 a[2], bfr[4];
            #pragma unroll
            for (int i = 0; i < 2; i++) a[i] = *(const bf16x8*)&As[w * 32 + i * 16 + lr][lg * 8];
            #pragma unroll
            for (int j = 0; j < 4; j++) bfr[j] = *(const bf16x8*)&Bs[j * 16 + lr][lg * 8];
            #pragma unroll
            for (int i = 0; i < 2; i++)
                #pragma unroll
                for (int j = 0; j < 4; j++)
                    acc[i][j] = __builtin_amdgcn_mfma_f32_16x16x32_bf16(a[i], bfr[j], acc[i][j], 0, 0, 0);
            __syncthreads();
        }
        #pragma unroll
        for (int i = 0; i < 2; i++) {
            #pragma unroll
            for (int j = 0; j < 4; j++) {
                int c = c0 + j * 16 + lr;
                int h = c >> 6, d = c & 63;
                float bb = bias[c];
                #pragma unroll
                for (int r = 0; r < 4; r++) {
                    int m = m0 + w * 32 + i * 16 + lg * 4 + r;
                    float v = (acc[i][j][r] + bb) * scale;
                    dst[((size_t)h * L_SEQ + m) * DK + d] = (bf16)v;
                }
            }
        }
    } else {
        // ---- V^T path: vt[c][m] ----
        const int bid = blockIdx.x - 768;
        const int bc = bid % 12;
        const int bmm = bid / 12;
        const int c0 = bc * 64;
        const int mm0 = bmm * 128;

        f32x4 acc[8];
        #pragma unroll
        for (int j = 0; j < 8; j++) acc[j] = (f32x4){0.f, 0.f, 0.f, 0.f};

        for (int kk = 0; kk < DMODEL; kk += 32) {
            #pragma unroll
            for (int p = 0; p < 4; ++p) {
                int id = t + p * 256;
                int row = id >> 3, c4 = id & 7;
                const float4 v = *(const float4*)(x + (size_t)(mm0 + row) * DMODEL + kk + c4 * 4);
                bf16x4 b; b[0] = (bf16)v.x; b[1] = (bf16)v.y; b[2] = (bf16)v.z; b[3] = (bf16)v.w;
                *(bf16x4*)&As[row][c4 * 4] = b;
            }
            #pragma unroll
            for (int p = 0; p < 8; ++p) {
                int id = t + p * 256;
                int n = id & 63, kr = id >> 6;
                Bs[n][kr] = (bf16)w_v[(size_t)(kk + kr) * DMODEL + c0 + n];
            }
            __syncthreads();
            bf16x8 a = *(const bf16x8*)&Bs[w * 16 + lr][lg * 8];
            #pragma unroll
            for (int j = 0; j < 8; j++) {
                bf16x8 b = *(const bf16x8*)&As[j * 16 + lr][lg * 8];
                acc[j] = __builtin_amdgcn_mfma_f32_16x16x32_bf16(a, b, acc[j], 0, 0, 0);
            }
            __syncthreads();
        }
        #pragma unroll
        for (int j = 0; j < 8; j++) {
            int m = mm0 + j * 16 + lr;
            #pragma unroll
            for (int r = 0; r < 4; r++) {
                int c = c0 + w * 16 + lg * 4 + r;
                float v = acc[j][r] + b_v[c];
                vt[(size_t)c * L_SEQ + m] = (bf16)v;
            }
        }
    }
}

// -------------------- Kernel B: causal flash attention --------------------
// 4 waves/block, 64 q-rows/block (16 per wave). Swapped QK^T (mfma(K,Q) -> S^T)
// so each lane owns one q-row's scores: softmax = in-reg tree + 2 shfls.
__global__ __launch_bounds__(256) void attn_kernel(
    const bf16* __restrict__ qbuf, const bf16* __restrict__ kbuf,
    const bf16* __restrict__ vt, bf16* __restrict__ obuf)
{
    __shared__ bf16 Ks[64][72];     // K tile [kv][d]
    __shared__ bf16 Vs[64][72];     // V^T tile [d][kv]
    __shared__ bf16 Ps[4][16][72];  // per-wave P [q][kv]  (kv extent 64 -> dim 72!)

    const int bid = blockIdx.x;
    const int h  = bid % NH;
    const int qt = 63 - (bid / NH);       // LPT: heavy q-tiles first
    const int q0 = qt * 64;
    const int nt = qt + 1;

    const int t = threadIdx.x;
    const int w = t >> 6, l = t & 63;
    const int lg = l >> 4, lr = l & 15;

    // Q fragment (B-operand of swapped mfma): q-row = q0 + w*16 + lr
    const size_t qrow = (size_t)h * L_SEQ + q0 + w * 16 + lr;
    const bf16x8 qa0 = *(const bf16x8*)(qbuf + qrow * DK + 0  + lg * 8);
    const bf16x8 qa1 = *(const bf16x8*)(qbuf + qrow * DK + 32 + lg * 8);

    f32x4 acc[4];
    #pragma unroll
    for (int j = 0; j < 4; j++) acc[j] = (f32x4){0.f, 0.f, 0.f, 0.f};
    float run_m = -1e30f, run_s = 0.0f;

    const bf16* kb_base = kbuf + (size_t)h * L_SEQ * DK;
    const bf16* vt_base = vt + (size_t)h * DK * L_SEQ;

    // prologue: tile 0 into regs
    bf16x8 k8[2], v8[2];
    #pragma unroll
    for (int p = 0; p < 2; ++p) {
        int id = t + p * 256;
        int row = id >> 3, ch = id & 7;
        k8[p] = *(const bf16x8*)(kb_base + (size_t)row * DK + ch * 8);
        v8[p] = *(const bf16x8*)(vt_base + (size_t)row * L_SEQ + ch * 8);
    }

    for (int cur = 0; cur < nt; ++cur) {
        __syncthreads();                  // prev compute done; LDS reusable
        #pragma unroll
        for (int p = 0; p < 2; ++p) {
            int id = t + p * 256;
            int row = id >> 3, ch = id & 7;
            *(bf16x8*)&Ks[row][ch * 8] = k8[p];
            *(bf16x8*)&Vs[row][ch * 8] = v8[p];
        }
        __syncthreads();
        if (cur + 1 < nt) {               // prefetch next tile (overlaps compute)
            #pragma unroll
            for (int p = 0; p < 2; ++p) {
                int id = t + p * 256;
                int row = id >> 3, ch = id & 7;
                k8[p] = *(const bf16x8*)(kb_base + (size_t)((cur + 1) * 64 + row) * DK + ch * 8);
                v8[p] = *(const bf16x8*)(vt_base + (size_t)row * L_SEQ + (cur + 1) * 64 + ch * 8);
            }
        }
        // S^T = K Q^T : s[j][r] -> kv-local = j*16 + lg*4 + r, q-local = lr
        f32x4 s[4];
        #pragma unroll
        for (int j = 0; j < 4; j++) s[j] = (f32x4){0.f, 0.f, 0.f, 0.f};
        #pragma unroll
        for (int dh = 0; dh < 2; ++dh) {
            const bf16x8 qa = dh ? qa1 : qa0;
            #pragma unroll
            for (int j = 0; j < 4; j++) {
                bf16x8 kb = *(const bf16x8*)&Ks[j * 16 + lr][dh * 32 + lg * 8];
                s[j] = __builtin_amdgcn_mfma_f32_16x16x32_bf16(kb, qa, s[j], 0, 0, 0);
            }
        }
        if (cur == qt) {                  // causal mask on diagonal tile
            const int qoff = w * 16 + lr;
            #pragma unroll
            for (int j = 0; j < 4; j++)
                #pragma unroll
                for (int r = 0; r < 4; r++)
                    if (j * 16 + lg * 4 + r > qoff) s[j][r] = -3e30f;
        }
        // row max: in-register tree + 2 shfls (lanes lr, lr+16, lr+32, lr+48)
        float mx0 = fmaxf(fmaxf(s[0][0], s[0][1]), fmaxf(s[0][2], s[0][3]));
        float mx1 = fmaxf(fmaxf(s[1][0], s[1][1]), fmaxf(s[1][2], s[1][3]));
        float mx2 = fmaxf(fmaxf(s[2][0], s[2][1]), fmaxf(s[2][2], s[2][3]));
        float mx3 = fmaxf(fmaxf(s[3][0], s[3][1]), fmaxf(s[3][2], s[3][3]));
        float mx = fmaxf(fmaxf(mx0, mx1), fmaxf(mx2, mx3));
        mx = fmaxf(mx, __shfl_xor(mx, 16));
        mx = fmaxf(mx, __shfl_xor(mx, 32));
        const float nm = fmaxf(run_m, mx);
        const float scq = exp2f(run_m - nm);
        run_m = nm;
        #pragma unroll
        for (int j = 0; j < 4; j++)
            #pragma unroll
            for (int r = 0; r < 4; r++) s[j][r] = exp2f(s[j][r] - nm);
        float ps0 = (s[0][0] + s[0][1]) + (s[0][2] + s[0][3]);
        float ps1 = (s[1][0] + s[1][1]) + (s[1][2] + s[1][3]);
        float ps2 = (s[2][0] + s[2][1]) + (s[2][2] + s[2][3]);
        float ps3 = (s[3][0] + s[3][1]) + (s[3][2] + s[3][3]);
        float ps = (ps0 + ps1) + (ps2 + ps3);
        ps += __shfl_xor(ps, 16);
        ps += __shfl_xor(ps, 32);
        run_s = run_s * scq + ps;
        // P -> LDS (wave-private, vectorized): Ps[w][q=lr][kv]
        #pragma unroll
        for (int j = 0; j < 4; j++) {
            bf16x4 pk;
            pk[0] = (bf16)s[j][0]; pk[1] = (bf16)s[j][1];
            pk[2] = (bf16)s[j][2]; pk[3] = (bf16)s[j][3];
            *(bf16x4*)&Ps[w][lr][j * 16 + lg * 4] = pk;
        }
        // rescale O accumulators (skip when no row max changed)
        if (!__all(scq == 1.0f)) {
            float sc0 = __shfl(scq, lg * 4 + 0);
            float sc1 = __shfl(scq, lg * 4 + 1);
            float sc2 = __shfl(scq, lg * 4 + 2);
            float sc3 = __shfl(scq, lg * 4 + 3);
            #pragma unroll
            for (int jd = 0; jd < 4; jd++) {
                acc[jd][0] *= sc0; acc[jd][1] *= sc1;
                acc[jd][2] *= sc2; acc[jd][3] *= sc3;
            }
        }
        // PV: O += P V
        #pragma unroll
        for (int dh = 0; dh < 2; ++dh) {
            bf16x8 pa = *(const bf16x8*)&Ps[w][lr][dh * 32 + lg * 8];
            #pragma unroll
            for (int jd = 0; jd < 4; jd++) {
                bf16x8 vb = *(const bf16x8*)&Vs[jd * 16 + lr][dh * 32 + lg * 8];
                acc[jd] = __builtin_amdgcn_mfma_f32_16x16x32_bf16(pa, vb, acc[jd], 0, 0, 0);
            }
        }
    }

    // normalize + write concat-head layout [L][768] bf16
    float rs[4];
    #pragma unroll
    for (int r = 0; r < 4; r++) rs[r] = __shfl(run_s, lg * 4 + r);
    #pragma unroll
    for (int jd = 0; jd < 4; jd++) {
        #pragma unroll
        for (int r = 0; r < 4; r++) {
            int m = q0 + w * 16 + lg * 4 + r;
            obuf[(size_t)m * DMODEL + h * DK + jd * 16 + lr] = (bf16)(acc[jd][r] / rs[r]);
        }
    }
}

// -------------------- Kernel C: output projection (fp32 out) --------------------
__global__ __launch_bounds__(256) void out_proj_kernel(
    const bf16* __restrict__ obuf, const float* __restrict__ w_o,
    const float* __restrict__ b_o, float* __restrict__ out)
{
    __shared__ bf16 As[128][40];
    __shared__ bf16 Bts[64][40];
    const int bn = blockIdx.x % 12;
    const int bm = blockIdx.x / 12;
    const int m0 = bm * 128, c0 = bn * 64;
    const int t = threadIdx.x;
    const int w = t >> 6, l = t & 63, lg = l >> 4, lr = l & 15;

    f32x4 acc[2][4];
    #pragma unroll
    for (int i = 0; i < 2; i++)
        #pragma unroll
        for (int j = 0; j < 4; j++) acc[i][j] = (f32x4){0.f, 0.f, 0.f, 0.f};

    for (int kk = 0; kk < DMODEL; kk += 32) {
        #pragma unroll
        for (int p = 0; p < 2; ++p) {
            int id = t + p * 256;
            int row = id >> 2, ch = id & 3;
            bf16x8 v8 = *(const bf16x8*)(obuf + (size_t)(m0 + row) * DMODEL + kk + ch * 8);
            *(bf16x8*)&As[row][ch * 8] = v8;
        }
        #pragma unroll
        for (int p = 0; p < 8; ++p) {
            int id = t + p * 256;
            int n = id & 63, kr = id >> 6;
            Bts[n][kr] = (bf16)w_o[(size_t)(kk + kr) * DMODEL + c0 + n];
        }
        __syncthreads();
        bf16x8 a[2], bfr[4];
        #pragma unroll
        for (int i = 0; i < 2; i++) a[i] = *(const bf16x8*)&As[w * 32 + i * 16 + lr][lg * 8];
        #pragma unroll
        for (int j = 0; j < 4; j++) bfr[j] = *(const bf16x8*)&Bts[j * 16 + lr][lg * 8];
        #pragma unroll
        for (int i = 0; i < 2; i++)
            #pragma unroll
            for (int j = 0; j < 4; j++)
                acc[i][j] = __builtin_amdgcn_mfma_f32_16x16x32_bf16(a[i], bfr[j], acc[i][j], 0, 0, 0);
        __syncthreads();
    }
    #pragma unroll
    for (int i = 0; i < 2; i++) {
        #pragma unroll
        for (int j = 0; j < 4; j++) {
            int c = c0 + j * 16 + lr;
            float bb = b_o[c];
            #pragma unroll
            for (int r = 0; r < 4; r++) {
                int m = m0 + w * 32 + i * 16 + lg * 4 + r;
                out[(size_t)m * DMODEL + c] = acc[i][j][r] + bb;
            }
        }
    }
}

extern "C" void kernel_launch(void* const* d_in, const int* in_sizes, int n_in,
                              void* d_out, int out_size, void* d_ws, size_t ws_size,
                              hipStream_t stream) {
    const float* x   = (const float*)d_in[0];
    const float* w_q = (const float*)d_in[1];
    const float* b_q = (const float*)d_in[2];
    const float* w_k = (const float*)d_in[3];
    const float* b_k = (const float*)d_in[4];
    const float* w_v = (const float*)d_in[5];
    const float* b_v = (const float*)d_in[6];
    const float* w_o = (const float*)d_in[7];
    const float* b_o = (const float*)d_in[8];
    float* out = (float*)d_out;

    char* ws = (char*)d_ws;
    const size_t SZ = (size_t)NH * L_SEQ * DK * sizeof(bf16);
    bf16* qbuf = (bf16*)(ws);
    bf16* kbuf = (bf16*)(ws + SZ);
    bf16* vt   = (bf16*)(ws + 2 * SZ);
    bf16* obuf = (bf16*)(ws + 3 * SZ);

    proj_kernel<<<dim3(1152), dim3(256), 0, stream>>>(x, w_q, b_q, w_k, b_k, w_v, b_v, qbuf, kbuf, vt);
    attn_kernel<<<dim3(768), dim3(256), 0, stream>>>(qbuf, kbuf, vt, obuf);
    out_proj_kernel<<<dim3(384), dim3(256), 0, stream>>>(obuf, w_o, b_o, out);
}

// Round 5
// 147.075 us; speedup vs baseline: 2.1509x; 1.1485x over previous
//
#include <hip/hip_runtime.h>

#define L_SEQ 4096
#define DMODEL 768
#define NH 12
#define DK 64

typedef __bf16 bf16;
typedef __bf16 bf16x8 __attribute__((ext_vector_type(8)));
typedef __bf16 bf16x4 __attribute__((ext_vector_type(4)));
typedef float f32x4 __attribute__((ext_vector_type(4)));

#define QSCALE 0.1803368801111204f  /* 0.125 * log2(e): exp2 domain */

// -------------------- Kernel A: fused Q/K/V projections --------------------
// bid < 768: Q/K path (128x64 tiles over [4096,1536]); bid >= 768: V^T path.
__global__ __launch_bounds__(256) void proj_kernel(
    const float* __restrict__ x,
    const float* __restrict__ w_q, const float* __restrict__ b_q,
    const float* __restrict__ w_k, const float* __restrict__ b_k,
    const float* __restrict__ w_v, const float* __restrict__ b_v,
    bf16* __restrict__ qbuf, bf16* __restrict__ kbuf, bf16* __restrict__ vt)
{
    __shared__ bf16 As[128][40];
    __shared__ bf16 Bs[64][40];
    const int t = threadIdx.x;
    const int w = t >> 6, l = t & 63;
    const int lg = l >> 4, lr = l & 15;

    if (blockIdx.x < 768) {
        // ---- Q/K path ----
        const int bn = blockIdx.x % 24;
        const int bm = blockIdx.x / 24;
        const int m0 = bm * 128;
        const int gn0 = bn * 64;
        const int sel = gn0 / DMODEL;        // 0=Q, 1=K
        const int c0 = gn0 % DMODEL;
        const float* W = sel ? w_k : w_q;
        const float* bias = sel ? b_k : b_q;
        bf16* dst = sel ? kbuf : qbuf;
        const float scale = sel ? 1.0f : QSCALE;

        f32x4 acc[2][4];
        #pragma unroll
        for (int i = 0; i < 2; i++)
            #pragma unroll
            for (int j = 0; j < 4; j++) acc[i][j] = (f32x4){0.f, 0.f, 0.f, 0.f};

        for (int kk = 0; kk < DMODEL; kk += 32) {
            #pragma unroll
            for (int p = 0; p < 4; ++p) {
                int id = t + p * 256;
                int row = id >> 3, c4 = id & 7;
                const float4 v = *(const float4*)(x + (size_t)(m0 + row) * DMODEL + kk + c4 * 4);
                bf16x4 b; b[0] = (bf16)v.x; b[1] = (bf16)v.y; b[2] = (bf16)v.z; b[3] = (bf16)v.w;
                *(bf16x4*)&As[row][c4 * 4] = b;
            }
            #pragma unroll
            for (int p = 0; p < 8; ++p) {
                int id = t + p * 256;
                int n = id & 63, kr = id >> 6;
                Bs[n][kr] = (bf16)W[(size_t)(kk + kr) * DMODEL + c0 + n];
            }
            __syncthreads();
            bf16x8 a[2], bfr[4];
            #pragma unroll
            for (int i = 0; i < 2; i++) a[i] = *(const bf16x8*)&As[w * 32 + i * 16 + lr][lg * 8];
            #pragma unroll
            for (int j = 0; j < 4; j++) bfr[j] = *(const bf16x8*)&Bs[j * 16 + lr][lg * 8];
            #pragma unroll
            for (int i = 0; i < 2; i++)
                #pragma unroll
                for (int j = 0; j < 4; j++)
                    acc[i][j] = __builtin_amdgcn_mfma_f32_16x16x32_bf16(a[i], bfr[j], acc[i][j], 0, 0, 0);
            __syncthreads();
        }
        #pragma unroll
        for (int i = 0; i < 2; i++) {
            #pragma unroll
            for (int j = 0; j < 4; j++) {
                int c = c0 + j * 16 + lr;
                int h = c >> 6, d = c & 63;
                float bb = bias[c];
                #pragma unroll
                for (int r = 0; r < 4; r++) {
                    int m = m0 + w * 32 + i * 16 + lg * 4 + r;
                    float v = (acc[i][j][r] + bb) * scale;
                    dst[((size_t)h * L_SEQ + m) * DK + d] = (bf16)v;
                }
            }
        }
    } else {
        // ---- V^T path: vt[c][m] ----
        const int bid = blockIdx.x - 768;
        const int bc = bid % 12;
        const int bmm = bid / 12;
        const int c0 = bc * 64;
        const int mm0 = bmm * 128;

        f32x4 acc[8];
        #pragma unroll
        for (int j = 0; j < 8; j++) acc[j] = (f32x4){0.f, 0.f, 0.f, 0.f};

        for (int kk = 0; kk < DMODEL; kk += 32) {
            #pragma unroll
            for (int p = 0; p < 4; ++p) {
                int id = t + p * 256;
                int row = id >> 3, c4 = id & 7;
                const float4 v = *(const float4*)(x + (size_t)(mm0 + row) * DMODEL + kk + c4 * 4);
                bf16x4 b; b[0] = (bf16)v.x; b[1] = (bf16)v.y; b[2] = (bf16)v.z; b[3] = (bf16)v.w;
                *(bf16x4*)&As[row][c4 * 4] = b;
            }
            #pragma unroll
            for (int p = 0; p < 8; ++p) {
                int id = t + p * 256;
                int n = id & 63, kr = id >> 6;
                Bs[n][kr] = (bf16)w_v[(size_t)(kk + kr) * DMODEL + c0 + n];
            }
            __syncthreads();
            bf16x8 a = *(const bf16x8*)&Bs[w * 16 + lr][lg * 8];
            #pragma unroll
            for (int j = 0; j < 8; j++) {
                bf16x8 b = *(const bf16x8*)&As[j * 16 + lr][lg * 8];
                acc[j] = __builtin_amdgcn_mfma_f32_16x16x32_bf16(a, b, acc[j], 0, 0, 0);
            }
            __syncthreads();
        }
        #pragma unroll
        for (int j = 0; j < 8; j++) {
            int m = mm0 + j * 16 + lr;
            #pragma unroll
            for (int r = 0; r < 4; r++) {
                int c = c0 + w * 16 + lg * 4 + r;
                float v = acc[j][r] + b_v[c];
                vt[(size_t)c * L_SEQ + m] = (bf16)v;
            }
        }
    }
}

// -------------------- Kernel B: causal flash attention --------------------
// 8 waves/block, 64 q-rows (4 waves x 16 rows per group). Wave-groups 0/1
// split kv tiles by parity; (m,s,acc) merged via LDS at the end.
// All LDS tiles XOR-swizzled (byte ^= (row&7)<<4) on 128B rows: conflict-free.
__global__ __launch_bounds__(512) void attn_kernel(
    const bf16* __restrict__ qbuf, const bf16* __restrict__ kbuf,
    const bf16* __restrict__ vt, bf16* __restrict__ obuf)
{
    __shared__ __align__(16) char lds[49152];
    // carve: Ks[2] @0 (2x8KB), Vs[2] @16384 (2x8KB), Ps[8] @32768 (8x2KB)
    // merge aliases (post-loop only): mergeAcc @0 [256][17]f32, mergeMS @17408 [256][2]f32

    const int bid = blockIdx.x;
    const int h  = bid % NH;
    const int qt = 63 - (bid / NH);
    const int q0 = qt * 64;
    const int nt = qt + 1;
    const int nit = (nt + 1) >> 1;

    const int t = threadIdx.x;
    const int w = t >> 6;                 // wave 0..7
    const int g = w >> 2;                 // kv-parity group
    const int wg = w & 3;                 // wave-in-group -> q sub-rows
    const int l = t & 63;
    const int lg = l >> 4, lr = l & 15;
    const int tg = t & 255;               // thread-in-group
    const int sw = (lr & 7) << 4;         // read-side XOR (row&7 == lr&7 for our reads)

    char* Kbase = lds + (size_t)g * 8192;
    char* Vbase = lds + 16384 + (size_t)g * 8192;
    char* Pbase = lds + 32768 + (size_t)w * 2048;
    float* mergeAcc = (float*)lds;
    float* mergeMS  = (float*)(lds + 17408);

    // Q fragment (B-operand of swapped mfma): q-row = q0 + wg*16 + lr
    const size_t qrow = (size_t)h * L_SEQ + q0 + wg * 16 + lr;
    const bf16x8 qa0 = *(const bf16x8*)(qbuf + qrow * DK + 0  + lg * 8);
    const bf16x8 qa1 = *(const bf16x8*)(qbuf + qrow * DK + 32 + lg * 8);

    f32x4 acc[4];
    #pragma unroll
    for (int j = 0; j < 4; j++) acc[j] = (f32x4){0.f, 0.f, 0.f, 0.f};
    float run_m = -1e30f, run_s = 0.0f;

    const bf16* kb_base = kbuf + (size_t)h * L_SEQ * DK;
    const bf16* vt_base = vt + (size_t)h * DK * L_SEQ;

    // prologue: this group's first tile into regs
    bf16x8 k8[2], v8[2];
    if (g < nt) {
        #pragma unroll
        for (int p = 0; p < 2; ++p) {
            int id = tg + p * 256;
            int row = id >> 3, ch = id & 7;
            k8[p] = *(const bf16x8*)(kb_base + (size_t)(g * 64 + row) * DK + ch * 8);
            v8[p] = *(const bf16x8*)(vt_base + (size_t)row * L_SEQ + g * 64 + ch * 8);
        }
    }

    for (int it = 0; it < nit; ++it) {
        const int cur = 2 * it + g;
        const bool active = (cur < nt);
        __syncthreads();                       // prior compute done; tiles reusable
        if (active) {
            #pragma unroll
            for (int p = 0; p < 2; ++p) {
                int id = tg + p * 256;
                int row = id >> 3, ch = id & 7;
                int so = (ch * 16) ^ ((row & 7) << 4);
                *(bf16x8*)(Kbase + row * 128 + so) = k8[p];
                *(bf16x8*)(Vbase + row * 128 + so) = v8[p];
            }
        }
        __syncthreads();
        const int nxt = cur + 2;               // prefetch next tile (overlaps compute)
        if (nxt < nt) {
            #pragma unroll
            for (int p = 0; p < 2; ++p) {
                int id = tg + p * 256;
                int row = id >> 3, ch = id & 7;
                k8[p] = *(const bf16x8*)(kb_base + (size_t)(nxt * 64 + row) * DK + ch * 8);
                v8[p] = *(const bf16x8*)(vt_base + (size_t)row * L_SEQ + nxt * 64 + ch * 8);
            }
        }
        if (active) {
            // S^T = K Q^T : s[j][r] -> kv-local = j*16 + lg*4 + r, q-local = lr
            f32x4 s[4];
            #pragma unroll
            for (int j = 0; j < 4; j++) s[j] = (f32x4){0.f, 0.f, 0.f, 0.f};
            #pragma unroll
            for (int dh = 0; dh < 2; ++dh) {
                const bf16x8 qa = dh ? qa1 : qa0;
                #pragma unroll
                for (int j = 0; j < 4; j++) {
                    bf16x8 kb = *(const bf16x8*)(Kbase + (j * 16 + lr) * 128 + ((dh * 64 + lg * 16) ^ sw));
                    s[j] = __builtin_amdgcn_mfma_f32_16x16x32_bf16(kb, qa, s[j], 0, 0, 0);
                }
            }
            if (cur == qt) {                   // causal mask on diagonal tile
                const int qoff = wg * 16 + lr;
                #pragma unroll
                for (int j = 0; j < 4; j++)
                    #pragma unroll
                    for (int r = 0; r < 4; r++)
                        if (j * 16 + lg * 4 + r > qoff) s[j][r] = -3e30f;
            }
            // row max: in-register tree + 2 shfls
            float mx0 = fmaxf(fmaxf(s[0][0], s[0][1]), fmaxf(s[0][2], s[0][3]));
            float mx1 = fmaxf(fmaxf(s[1][0], s[1][1]), fmaxf(s[1][2], s[1][3]));
            float mx2 = fmaxf(fmaxf(s[2][0], s[2][1]), fmaxf(s[2][2], s[2][3]));
            float mx3 = fmaxf(fmaxf(s[3][0], s[3][1]), fmaxf(s[3][2], s[3][3]));
            float mx = fmaxf(fmaxf(mx0, mx1), fmaxf(mx2, mx3));
            mx = fmaxf(mx, __shfl_xor(mx, 16));
            mx = fmaxf(mx, __shfl_xor(mx, 32));
            const float nm = fmaxf(run_m, mx);
            const float scq = exp2f(run_m - nm);
            run_m = nm;
            #pragma unroll
            for (int j = 0; j < 4; j++)
                #pragma unroll
                for (int r = 0; r < 4; r++) s[j][r] = exp2f(s[j][r] - nm);
            float ps0 = (s[0][0] + s[0][1]) + (s[0][2] + s[0][3]);
            float ps1 = (s[1][0] + s[1][1]) + (s[1][2] + s[1][3]);
            float ps2 = (s[2][0] + s[2][1]) + (s[2][2] + s[2][3]);
            float ps3 = (s[3][0] + s[3][1]) + (s[3][2] + s[3][3]);
            float ps = (ps0 + ps1) + (ps2 + ps3);
            ps += __shfl_xor(ps, 16);
            ps += __shfl_xor(ps, 32);
            run_s = run_s * scq + ps;
            // P -> LDS (wave-private, swizzled b64 stores): row = q = lr
            #pragma unroll
            for (int j = 0; j < 4; j++) {
                bf16x4 pk;
                pk[0] = (bf16)s[j][0]; pk[1] = (bf16)s[j][1];
                pk[2] = (bf16)s[j][2]; pk[3] = (bf16)s[j][3];
                *(bf16x4*)(Pbase + lr * 128 + ((j * 32 + lg * 8) ^ sw)) = pk;
            }
            // rescale O accumulators (skip when no row max changed)
            if (!__all(scq == 1.0f)) {
                float sc0 = __shfl(scq, lg * 4 + 0);
                float sc1 = __shfl(scq, lg * 4 + 1);
                float sc2 = __shfl(scq, lg * 4 + 2);
                float sc3 = __shfl(scq, lg * 4 + 3);
                #pragma unroll
                for (int jd = 0; jd < 4; jd++) {
                    acc[jd][0] *= sc0; acc[jd][1] *= sc1;
                    acc[jd][2] *= sc2; acc[jd][3] *= sc3;
                }
            }
            // PV: O += P V
            #pragma unroll
            for (int dh = 0; dh < 2; ++dh) {
                bf16x8 pa = *(const bf16x8*)(Pbase + lr * 128 + ((dh * 64 + lg * 16) ^ sw));
                #pragma unroll
                for (int jd = 0; jd < 4; jd++) {
                    bf16x8 vb = *(const bf16x8*)(Vbase + (jd * 16 + lr) * 128 + ((dh * 64 + lg * 16) ^ sw));
                    acc[jd] = __builtin_amdgcn_mfma_f32_16x16x32_bf16(pa, vb, acc[jd], 0, 0, 0);
                }
            }
        }
    }

    // ---- merge group partials (group1 -> LDS, group0 combines & writes) ----
    __syncthreads();
    if (g == 1) {
        float* base = mergeAcc + (size_t)(wg * 64 + l) * 17;
        #pragma unroll
        for (int jd = 0; jd < 4; jd++)
            #pragma unroll
            for (int r = 0; r < 4; r++) base[jd * 4 + r] = acc[jd][r];
        mergeMS[(wg * 64 + l) * 2 + 0] = run_m;
        mergeMS[(wg * 64 + l) * 2 + 1] = run_s;
    }
    __syncthreads();
    if (g == 0) {
        const float* base = mergeAcc + (size_t)(wg * 64 + l) * 17;
        const float mB = mergeMS[(wg * 64 + l) * 2 + 0];
        const float sB = mergeMS[(wg * 64 + l) * 2 + 1];
        const float mF = fmaxf(run_m, mB);
        const float sa = exp2f(run_m - mF);
        const float sb = exp2f(mB - mF);
        const float sT = run_s * sa + sB * sb;
        float a4[4], b4[4], rs[4];
        #pragma unroll
        for (int r = 0; r < 4; r++) {
            a4[r] = __shfl(sa, lg * 4 + r);
            b4[r] = __shfl(sb, lg * 4 + r);
            rs[r] = __shfl(sT, lg * 4 + r);
        }
        #pragma unroll
        for (int jd = 0; jd < 4; jd++) {
            #pragma unroll
            for (int r = 0; r < 4; r++) {
                float v = acc[jd][r] * a4[r] + base[jd * 4 + r] * b4[r];
                int m = q0 + wg * 16 + lg * 4 + r;
                obuf[(size_t)m * DMODEL + h * DK + jd * 16 + lr] = (bf16)(v / rs[r]);
            }
        }
    }
}

// -------------------- Kernel C: output projection (fp32 out) --------------------
__global__ __launch_bounds__(256) void out_proj_kernel(
    const bf16* __restrict__ obuf, const float* __restrict__ w_o,
    const float* __restrict__ b_o, float* __restrict__ out)
{
    __shared__ bf16 As[128][40];
    __shared__ bf16 Bts[64][40];
    const int bn = blockIdx.x % 12;
    const int bm = blockIdx.x / 12;
    const int m0 = bm * 128, c0 = bn * 64;
    const int t = threadIdx.x;
    const int w = t >> 6, l = t & 63, lg = l >> 4, lr = l & 15;

    f32x4 acc[2][4];
    #pragma unroll
    for (int i = 0; i < 2; i++)
        #pragma unroll
        for (int j = 0; j < 4; j++) acc[i][j] = (f32x4){0.f, 0.f, 0.f, 0.f};

    for (int kk = 0; kk < DMODEL; kk += 32) {
        #pragma unroll
        for (int p = 0; p < 2; ++p) {
            int id = t + p * 256;
            int row = id >> 2, ch = id & 3;
            bf16x8 v8 = *(const bf16x8*)(obuf + (size_t)(m0 + row) * DMODEL + kk + ch * 8);
            *(bf16x8*)&As[row][ch * 8] = v8;
        }
        #pragma unroll
        for (int p = 0; p < 8; ++p) {
            int id = t + p * 256;
            int n = id & 63, kr = id >> 6;
            Bts[n][kr] = (bf16)w_o[(size_t)(kk + kr) * DMODEL + c0 + n];
        }
        __syncthreads();
        bf16x8 a[2], bfr[4];
        #pragma unroll
        for (int i = 0; i < 2; i++) a[i] = *(const bf16x8*)&As[w * 32 + i * 16 + lr][lg * 8];
        #pragma unroll
        for (int j = 0; j < 4; j++) bfr[j] = *(const bf16x8*)&Bts[j * 16 + lr][lg * 8];
        #pragma unroll
        for (int i = 0; i < 2; i++)
            #pragma unroll
            for (int j = 0; j < 4; j++)
                acc[i][j] = __builtin_amdgcn_mfma_f32_16x16x32_bf16(a[i], bfr[j], acc[i][j], 0, 0, 0);
        __syncthreads();
    }
    #pragma unroll
    for (int i = 0; i < 2; i++) {
        #pragma unroll
        for (int j = 0; j < 4; j++) {
            int c = c0 + j * 16 + lr;
            float bb = b_o[c];
            #pragma unroll
            for (int r = 0; r < 4; r++) {
                int m = m0 + w * 32 + i * 16 + lg * 4 + r;
                out[(size_t)m * DMODEL + c] = acc[i][j][r] + bb;
            }
        }
    }
}

extern "C" void kernel_launch(void* const* d_in, const int* in_sizes, int n_in,
                              void* d_out, int out_size, void* d_ws, size_t ws_size,
                              hipStream_t stream) {
    const float* x   = (const float*)d_in[0];
    const float* w_q = (const float*)d_in[1];
    const float* b_q = (const float*)d_in[2];
    const float* w_k = (const float*)d_in[3];
    const float* b_k = (const float*)d_in[4];
    const float* w_v = (const float*)d_in[5];
    const float* b_v = (const float*)d_in[6];
    const float* w_o = (const float*)d_in[7];
    const float* b_o = (const float*)d_in[8];
    float* out = (float*)d_out;

    char* ws = (char*)d_ws;
    const size_t SZ = (size_t)NH * L_SEQ * DK * sizeof(bf16);
    bf16* qbuf = (bf16*)(ws);
    bf16* kbuf = (bf16*)(ws + SZ);
    bf16* vt   = (bf16*)(ws + 2 * SZ);
    bf16* obuf = (bf16*)(ws + 3 * SZ);

    proj_kernel<<<dim3(1152), dim3(256), 0, stream>>>(x, w_q, b_q, w_k, b_k, w_v, b_v, qbuf, kbuf, vt);
    attn_kernel<<<dim3(768), dim3(512), 0, stream>>>(qbuf, kbuf, vt, obuf);
    out_proj_kernel<<<dim3(384), dim3(256), 0, stream>>>(obuf, w_o, b_o, out);
}

// Round 6
// 123.609 us; speedup vs baseline: 2.5592x; 1.1898x over previous
//
#include <hip/hip_runtime.h>

#define L_SEQ 4096
#define DMODEL 768
#define NH 12
#define DK 64

typedef __bf16 bf16;
typedef __bf16 bf16x8 __attribute__((ext_vector_type(8)));
typedef __bf16 bf16x4 __attribute__((ext_vector_type(4)));
typedef float f32x4 __attribute__((ext_vector_type(4)));

#define QSCALE 0.1803368801111204f  /* 0.125 * log2(e): exp2 domain */

// -------------------- Kernel 0: prep --------------------
// bid < 576: transpose+cvt the 4 weight matrices fp32 [k][n] -> bf16 [n][k].
// bid >= 576: cvt x fp32 -> bf16 (768 blocks x 4096 elems).
__global__ __launch_bounds__(256) void prep_kernel(
    const float* __restrict__ x,
    const float* __restrict__ w_q, const float* __restrict__ w_k,
    const float* __restrict__ w_v, const float* __restrict__ w_o,
    bf16* __restrict__ xb, bf16* __restrict__ wqt, bf16* __restrict__ wkt,
    bf16* __restrict__ wvt, bf16* __restrict__ wot)
{
    const int bid = blockIdx.x;
    const int t = threadIdx.x;
    if (bid < 576) {
        __shared__ bf16 Ls[64][72];
        const int mat = bid / 144;
        const int tile = bid % 144;
        const int k0 = (tile / 12) * 64;
        const int c0 = (tile % 12) * 64;
        const float* W = mat == 0 ? w_q : mat == 1 ? w_k : mat == 2 ? w_v : w_o;
        bf16* WT = mat == 0 ? wqt : mat == 1 ? wkt : mat == 2 ? wvt : wot;
        #pragma unroll
        for (int p = 0; p < 4; ++p) {
            int id = t + p * 256;
            int r = id >> 4, c4 = id & 15;
            float4 v = *(const float4*)(W + (size_t)(k0 + r) * DMODEL + c0 + c4 * 4);
            bf16x4 b; b[0] = (bf16)v.x; b[1] = (bf16)v.y; b[2] = (bf16)v.z; b[3] = (bf16)v.w;
            *(bf16x4*)&Ls[r][c4 * 4] = b;
        }
        __syncthreads();
        #pragma unroll
        for (int p = 0; p < 2; ++p) {
            int id = t + p * 256;
            int crow = id >> 3, kc = id & 7;
            bf16x8 o;
            #pragma unroll
            for (int e = 0; e < 8; ++e) o[e] = Ls[kc * 8 + e][crow];
            *(bf16x8*)(WT + (size_t)(c0 + crow) * DMODEL + k0 + kc * 8) = o;
        }
    } else {
        const size_t base = (size_t)(bid - 576) * 4096;
        #pragma unroll
        for (int p = 0; p < 4; ++p) {
            size_t idx = base + (size_t)(t + p * 256) * 4;
            float4 v = *(const float4*)(x + idx);
            bf16x4 b; b[0] = (bf16)v.x; b[1] = (bf16)v.y; b[2] = (bf16)v.z; b[3] = (bf16)v.w;
            *(bf16x4*)(xb + idx) = b;
        }
    }
}

// -------------------- Kernel A: fused Q/K/V projections (bf16 operands, BK=64) ----
// bid < 768: Q/K path (128x64 tiles over [4096,1536]); bid >= 768: V^T path.
__global__ __launch_bounds__(256) void proj_kernel(
    const bf16* __restrict__ xb,
    const bf16* __restrict__ wqt, const bf16* __restrict__ wkt, const bf16* __restrict__ wvt,
    const float* __restrict__ b_q, const float* __restrict__ b_k, const float* __restrict__ b_v,
    bf16* __restrict__ qbuf, bf16* __restrict__ kbuf, bf16* __restrict__ vt)
{
    __shared__ bf16 As[128][72];
    __shared__ bf16 Bs[64][72];
    const int t = threadIdx.x;
    const int w = t >> 6, l = t & 63;
    const int lg = l >> 4, lr = l & 15;

    if (blockIdx.x < 768) {
        // ---- Q/K path ----
        const int bn = blockIdx.x % 24;
        const int bm = blockIdx.x / 24;
        const int m0 = bm * 128;
        const int gn0 = bn * 64;
        const int sel = gn0 / DMODEL;        // 0=Q, 1=K
        const int c0 = gn0 % DMODEL;
        const bf16* WT = sel ? wkt : wqt;
        const float* bias = sel ? b_k : b_q;
        bf16* dst = sel ? kbuf : qbuf;
        const float scale = sel ? 1.0f : QSCALE;

        f32x4 acc[2][4];
        #pragma unroll
        for (int i = 0; i < 2; i++)
            #pragma unroll
            for (int j = 0; j < 4; j++) acc[i][j] = (f32x4){0.f, 0.f, 0.f, 0.f};

        for (int kk = 0; kk < DMODEL; kk += 64) {
            #pragma unroll
            for (int p = 0; p < 4; ++p) {
                int id = t + p * 256;
                int row = id >> 3, ch = id & 7;
                *(bf16x8*)&As[row][ch * 8] =
                    *(const bf16x8*)(xb + (size_t)(m0 + row) * DMODEL + kk + ch * 8);
            }
            #pragma unroll
            for (int p = 0; p < 2; ++p) {
                int id = t + p * 256;
                int n = id >> 3, ch = id & 7;
                *(bf16x8*)&Bs[n][ch * 8] =
                    *(const bf16x8*)(WT + (size_t)(c0 + n) * DMODEL + kk + ch * 8);
            }
            __syncthreads();
            #pragma unroll
            for (int ks = 0; ks < 2; ++ks) {
                bf16x8 a[2], bfr[4];
                #pragma unroll
                for (int i = 0; i < 2; i++) a[i] = *(const bf16x8*)&As[w * 32 + i * 16 + lr][ks * 32 + lg * 8];
                #pragma unroll
                for (int j = 0; j < 4; j++) bfr[j] = *(const bf16x8*)&Bs[j * 16 + lr][ks * 32 + lg * 8];
                #pragma unroll
                for (int i = 0; i < 2; i++)
                    #pragma unroll
                    for (int j = 0; j < 4; j++)
                        acc[i][j] = __builtin_amdgcn_mfma_f32_16x16x32_bf16(a[i], bfr[j], acc[i][j], 0, 0, 0);
            }
            __syncthreads();
        }
        #pragma unroll
        for (int i = 0; i < 2; i++) {
            #pragma unroll
            for (int j = 0; j < 4; j++) {
                int c = c0 + j * 16 + lr;
                int h = c >> 6, d = c & 63;
                float bb = bias[c];
                #pragma unroll
                for (int r = 0; r < 4; r++) {
                    int m = m0 + w * 32 + i * 16 + lg * 4 + r;
                    float v = (acc[i][j][r] + bb) * scale;
                    dst[((size_t)h * L_SEQ + m) * DK + d] = (bf16)v;
                }
            }
        }
    } else {
        // ---- V^T path: vt[c][m] ----
        const int bid = blockIdx.x - 768;
        const int bc = bid % 12;
        const int bmm = bid / 12;
        const int c0 = bc * 64;
        const int mm0 = bmm * 128;

        f32x4 acc[8];
        #pragma unroll
        for (int j = 0; j < 8; j++) acc[j] = (f32x4){0.f, 0.f, 0.f, 0.f};

        for (int kk = 0; kk < DMODEL; kk += 64) {
            #pragma unroll
            for (int p = 0; p < 4; ++p) {
                int id = t + p * 256;
                int row = id >> 3, ch = id & 7;
                *(bf16x8*)&As[row][ch * 8] =
                    *(const bf16x8*)(xb + (size_t)(mm0 + row) * DMODEL + kk + ch * 8);
            }
            #pragma unroll
            for (int p = 0; p < 2; ++p) {
                int id = t + p * 256;
                int n = id >> 3, ch = id & 7;
                *(bf16x8*)&Bs[n][ch * 8] =
                    *(const bf16x8*)(wvt + (size_t)(c0 + n) * DMODEL + kk + ch * 8);
            }
            __syncthreads();
            #pragma unroll
            for (int ks = 0; ks < 2; ++ks) {
                bf16x8 a = *(const bf16x8*)&Bs[w * 16 + lr][ks * 32 + lg * 8];
                #pragma unroll
                for (int j = 0; j < 8; j++) {
                    bf16x8 b = *(const bf16x8*)&As[j * 16 + lr][ks * 32 + lg * 8];
                    acc[j] = __builtin_amdgcn_mfma_f32_16x16x32_bf16(a, b, acc[j], 0, 0, 0);
                }
            }
            __syncthreads();
        }
        #pragma unroll
        for (int j = 0; j < 8; j++) {
            int m = mm0 + j * 16 + lr;
            #pragma unroll
            for (int r = 0; r < 4; r++) {
                int c = c0 + w * 16 + lg * 4 + r;
                float v = acc[j][r] + b_v[c];
                vt[(size_t)c * L_SEQ + m] = (bf16)v;
            }
        }
    }
}

// -------------------- Kernel B: causal flash attention (UNCHANGED from r5) ------
__global__ __launch_bounds__(512) void attn_kernel(
    const bf16* __restrict__ qbuf, const bf16* __restrict__ kbuf,
    const bf16* __restrict__ vt, bf16* __restrict__ obuf)
{
    __shared__ __align__(16) char lds[49152];

    const int bid = blockIdx.x;
    const int h  = bid % NH;
    const int qt = 63 - (bid / NH);
    const int q0 = qt * 64;
    const int nt = qt + 1;
    const int nit = (nt + 1) >> 1;

    const int t = threadIdx.x;
    const int w = t >> 6;
    const int g = w >> 2;
    const int wg = w & 3;
    const int l = t & 63;
    const int lg = l >> 4, lr = l & 15;
    const int tg = t & 255;
    const int sw = (lr & 7) << 4;

    char* Kbase = lds + (size_t)g * 8192;
    char* Vbase = lds + 16384 + (size_t)g * 8192;
    char* Pbase = lds + 32768 + (size_t)w * 2048;
    float* mergeAcc = (float*)lds;
    float* mergeMS  = (float*)(lds + 17408);

    const size_t qrow = (size_t)h * L_SEQ + q0 + wg * 16 + lr;
    const bf16x8 qa0 = *(const bf16x8*)(qbuf + qrow * DK + 0  + lg * 8);
    const bf16x8 qa1 = *(const bf16x8*)(qbuf + qrow * DK + 32 + lg * 8);

    f32x4 acc[4];
    #pragma unroll
    for (int j = 0; j < 4; j++) acc[j] = (f32x4){0.f, 0.f, 0.f, 0.f};
    float run_m = -1e30f, run_s = 0.0f;

    const bf16* kb_base = kbuf + (size_t)h * L_SEQ * DK;
    const bf16* vt_base = vt + (size_t)h * DK * L_SEQ;

    bf16x8 k8[2], v8[2];
    if (g < nt) {
        #pragma unroll
        for (int p = 0; p < 2; ++p) {
            int id = tg + p * 256;
            int row = id >> 3, ch = id & 7;
            k8[p] = *(const bf16x8*)(kb_base + (size_t)(g * 64 + row) * DK + ch * 8);
            v8[p] = *(const bf16x8*)(vt_base + (size_t)row * L_SEQ + g * 64 + ch * 8);
        }
    }

    for (int it = 0; it < nit; ++it) {
        const int cur = 2 * it + g;
        const bool active = (cur < nt);
        __syncthreads();
        if (active) {
            #pragma unroll
            for (int p = 0; p < 2; ++p) {
                int id = tg + p * 256;
                int row = id >> 3, ch = id & 7;
                int so = (ch * 16) ^ ((row & 7) << 4);
                *(bf16x8*)(Kbase + row * 128 + so) = k8[p];
                *(bf16x8*)(Vbase + row * 128 + so) = v8[p];
            }
        }
        __syncthreads();
        const int nxt = cur + 2;
        if (nxt < nt) {
            #pragma unroll
            for (int p = 0; p < 2; ++p) {
                int id = tg + p * 256;
                int row = id >> 3, ch = id & 7;
                k8[p] = *(const bf16x8*)(kb_base + (size_t)(nxt * 64 + row) * DK + ch * 8);
                v8[p] = *(const bf16x8*)(vt_base + (size_t)row * L_SEQ + nxt * 64 + ch * 8);
            }
        }
        if (active) {
            f32x4 s[4];
            #pragma unroll
            for (int j = 0; j < 4; j++) s[j] = (f32x4){0.f, 0.f, 0.f, 0.f};
            #pragma unroll
            for (int dh = 0; dh < 2; ++dh) {
                const bf16x8 qa = dh ? qa1 : qa0;
                #pragma unroll
                for (int j = 0; j < 4; j++) {
                    bf16x8 kb = *(const bf16x8*)(Kbase + (j * 16 + lr) * 128 + ((dh * 64 + lg * 16) ^ sw));
                    s[j] = __builtin_amdgcn_mfma_f32_16x16x32_bf16(kb, qa, s[j], 0, 0, 0);
                }
            }
            if (cur == qt) {
                const int qoff = wg * 16 + lr;
                #pragma unroll
                for (int j = 0; j < 4; j++)
                    #pragma unroll
                    for (int r = 0; r < 4; r++)
                        if (j * 16 + lg * 4 + r > qoff) s[j][r] = -3e30f;
            }
            float mx0 = fmaxf(fmaxf(s[0][0], s[0][1]), fmaxf(s[0][2], s[0][3]));
            float mx1 = fmaxf(fmaxf(s[1][0], s[1][1]), fmaxf(s[1][2], s[1][3]));
            float mx2 = fmaxf(fmaxf(s[2][0], s[2][1]), fmaxf(s[2][2], s[2][3]));
            float mx3 = fmaxf(fmaxf(s[3][0], s[3][1]), fmaxf(s[3][2], s[3][3]));
            float mx = fmaxf(fmaxf(mx0, mx1), fmaxf(mx2, mx3));
            mx = fmaxf(mx, __shfl_xor(mx, 16));
            mx = fmaxf(mx, __shfl_xor(mx, 32));
            const float nm = fmaxf(run_m, mx);
            const float scq = exp2f(run_m - nm);
            run_m = nm;
            #pragma unroll
            for (int j = 0; j < 4; j++)
                #pragma unroll
                for (int r = 0; r < 4; r++) s[j][r] = exp2f(s[j][r] - nm);
            float ps0 = (s[0][0] + s[0][1]) + (s[0][2] + s[0][3]);
            float ps1 = (s[1][0] + s[1][1]) + (s[1][2] + s[1][3]);
            float ps2 = (s[2][0] + s[2][1]) + (s[2][2] + s[2][3]);
            float ps3 = (s[3][0] + s[3][1]) + (s[3][2] + s[3][3]);
            float ps = (ps0 + ps1) + (ps2 + ps3);
            ps += __shfl_xor(ps, 16);
            ps += __shfl_xor(ps, 32);
            run_s = run_s * scq + ps;
            #pragma unroll
            for (int j = 0; j < 4; j++) {
                bf16x4 pk;
                pk[0] = (bf16)s[j][0]; pk[1] = (bf16)s[j][1];
                pk[2] = (bf16)s[j][2]; pk[3] = (bf16)s[j][3];
                *(bf16x4*)(Pbase + lr * 128 + ((j * 32 + lg * 8) ^ sw)) = pk;
            }
            if (!__all(scq == 1.0f)) {
                float sc0 = __shfl(scq, lg * 4 + 0);
                float sc1 = __shfl(scq, lg * 4 + 1);
                float sc2 = __shfl(scq, lg * 4 + 2);
                float sc3 = __shfl(scq, lg * 4 + 3);
                #pragma unroll
                for (int jd = 0; jd < 4; jd++) {
                    acc[jd][0] *= sc0; acc[jd][1] *= sc1;
                    acc[jd][2] *= sc2; acc[jd][3] *= sc3;
                }
            }
            #pragma unroll
            for (int dh = 0; dh < 2; ++dh) {
                bf16x8 pa = *(const bf16x8*)(Pbase + lr * 128 + ((dh * 64 + lg * 16) ^ sw));
                #pragma unroll
                for (int jd = 0; jd < 4; jd++) {
                    bf16x8 vb = *(const bf16x8*)(Vbase + (jd * 16 + lr) * 128 + ((dh * 64 + lg * 16) ^ sw));
                    acc[jd] = __builtin_amdgcn_mfma_f32_16x16x32_bf16(pa, vb, acc[jd], 0, 0, 0);
                }
            }
        }
    }

    __syncthreads();
    if (g == 1) {
        float* base = mergeAcc + (size_t)(wg * 64 + l) * 17;
        #pragma unroll
        for (int jd = 0; jd < 4; jd++)
            #pragma unroll
            for (int r = 0; r < 4; r++) base[jd * 4 + r] = acc[jd][r];
        mergeMS[(wg * 64 + l) * 2 + 0] = run_m;
        mergeMS[(wg * 64 + l) * 2 + 1] = run_s;
    }
    __syncthreads();
    if (g == 0) {
        const float* base = mergeAcc + (size_t)(wg * 64 + l) * 17;
        const float mB = mergeMS[(wg * 64 + l) * 2 + 0];
        const float sB = mergeMS[(wg * 64 + l) * 2 + 1];
        const float mF = fmaxf(run_m, mB);
        const float sa = exp2f(run_m - mF);
        const float sb = exp2f(mB - mF);
        const float sT = run_s * sa + sB * sb;
        float a4[4], b4[4], rs[4];
        #pragma unroll
        for (int r = 0; r < 4; r++) {
            a4[r] = __shfl(sa, lg * 4 + r);
            b4[r] = __shfl(sb, lg * 4 + r);
            rs[r] = __shfl(sT, lg * 4 + r);
        }
        #pragma unroll
        for (int jd = 0; jd < 4; jd++) {
            #pragma unroll
            for (int r = 0; r < 4; r++) {
                float v = acc[jd][r] * a4[r] + base[jd * 4 + r] * b4[r];
                int m = q0 + wg * 16 + lg * 4 + r;
                obuf[(size_t)m * DMODEL + h * DK + jd * 16 + lr] = (bf16)(v / rs[r]);
            }
        }
    }
}

// -------------------- Kernel C: output projection (bf16 ops, BK=64, fp32 out) ---
__global__ __launch_bounds__(256) void out_proj_kernel(
    const bf16* __restrict__ obuf, const bf16* __restrict__ wot,
    const float* __restrict__ b_o, float* __restrict__ out)
{
    __shared__ bf16 As[128][72];
    __shared__ bf16 Bts[64][72];
    const int bn = blockIdx.x % 12;
    const int bm = blockIdx.x / 12;
    const int m0 = bm * 128, c0 = bn * 64;
    const int t = threadIdx.x;
    const int w = t >> 6, l = t & 63, lg = l >> 4, lr = l & 15;

    f32x4 acc[2][4];
    #pragma unroll
    for (int i = 0; i < 2; i++)
        #pragma unroll
        for (int j = 0; j < 4; j++) acc[i][j] = (f32x4){0.f, 0.f, 0.f, 0.f};

    for (int kk = 0; kk < DMODEL; kk += 64) {
        #pragma unroll
        for (int p = 0; p < 4; ++p) {
            int id = t + p * 256;
            int row = id >> 3, ch = id & 7;
            *(bf16x8*)&As[row][ch * 8] =
                *(const bf16x8*)(obuf + (size_t)(m0 + row) * DMODEL + kk + ch * 8);
        }
        #pragma unroll
        for (int p = 0; p < 2; ++p) {
            int id = t + p * 256;
            int n = id >> 3, ch = id & 7;
            *(bf16x8*)&Bts[n][ch * 8] =
                *(const bf16x8*)(wot + (size_t)(c0 + n) * DMODEL + kk + ch * 8);
        }
        __syncthreads();
        #pragma unroll
        for (int ks = 0; ks < 2; ++ks) {
            bf16x8 a[2], bfr[4];
            #pragma unroll
            for (int i = 0; i < 2; i++) a[i] = *(const bf16x8*)&As[w * 32 + i * 16 + lr][ks * 32 + lg * 8];
            #pragma unroll
            for (int j = 0; j < 4; j++) bfr[j] = *(const bf16x8*)&Bts[j * 16 + lr][ks * 32 + lg * 8];
            #pragma unroll
            for (int i = 0; i < 2; i++)
                #pragma unroll
                for (int j = 0; j < 4; j++)
                    acc[i][j] = __builtin_amdgcn_mfma_f32_16x16x32_bf16(a[i], bfr[j], acc[i][j], 0, 0, 0);
        }
        __syncthreads();
    }
    #pragma unroll
    for (int i = 0; i < 2; i++) {
        #pragma unroll
        for (int j = 0; j < 4; j++) {
            int c = c0 + j * 16 + lr;
            float bb = b_o[c];
            #pragma unroll
            for (int r = 0; r < 4; r++) {
                int m = m0 + w * 32 + i * 16 + lg * 4 + r;
                out[(size_t)m * DMODEL + c] = acc[i][j][r] + bb;
            }
        }
    }
}

extern "C" void kernel_launch(void* const* d_in, const int* in_sizes, int n_in,
                              void* d_out, int out_size, void* d_ws, size_t ws_size,
                              hipStream_t stream) {
    const float* x   = (const float*)d_in[0];
    const float* w_q = (const float*)d_in[1];
    const float* b_q = (const float*)d_in[2];
    const float* w_k = (const float*)d_in[3];
    const float* b_k = (const float*)d_in[4];
    const float* w_v = (const float*)d_in[5];
    const float* b_v = (const float*)d_in[6];
    const float* w_o = (const float*)d_in[7];
    const float* b_o = (const float*)d_in[8];
    float* out = (float*)d_out;

    char* ws = (char*)d_ws;
    const size_t SZ = (size_t)NH * L_SEQ * DK * sizeof(bf16);   // 6,291,456
    const size_t WTSZ = (size_t)DMODEL * DMODEL * sizeof(bf16); // 1,179,648
    bf16* qbuf = (bf16*)(ws);
    bf16* kbuf = (bf16*)(ws + SZ);
    bf16* vt   = (bf16*)(ws + 2 * SZ);
    bf16* obuf = (bf16*)(ws + 3 * SZ);
    bf16* xb   = (bf16*)(ws + 4 * SZ);
    bf16* wqt  = (bf16*)(ws + 5 * SZ);
    bf16* wkt  = (bf16*)(ws + 5 * SZ + WTSZ);
    bf16* wvt  = (bf16*)(ws + 5 * SZ + 2 * WTSZ);
    bf16* wot  = (bf16*)(ws + 5 * SZ + 3 * WTSZ);

    prep_kernel<<<dim3(1344), dim3(256), 0, stream>>>(x, w_q, w_k, w_v, w_o, xb, wqt, wkt, wvt, wot);
    proj_kernel<<<dim3(1152), dim3(256), 0, stream>>>(xb, wqt, wkt, wvt, b_q, b_k, b_v, qbuf, kbuf, vt);
    attn_kernel<<<dim3(768), dim3(512), 0, stream>>>(qbuf, kbuf, vt, obuf);
    out_proj_kernel<<<dim3(384), dim3(256), 0, stream>>>(obuf, wot, b_o, out);
}

// Round 7
// 115.335 us; speedup vs baseline: 2.7428x; 1.0717x over previous
//
#include <hip/hip_runtime.h>

#define L_SEQ 4096
#define DMODEL 768
#define NH 12
#define DK 64

typedef __bf16 bf16;
typedef __bf16 bf16x8 __attribute__((ext_vector_type(8)));
typedef __bf16 bf16x4 __attribute__((ext_vector_type(4)));
typedef float f32x4 __attribute__((ext_vector_type(4)));

#define QSCALE 0.1803368801111204f  /* 0.125 * log2(e): exp2 domain */
#define DEFER_THR 8.0f              /* defer-max threshold (exp2 domain): P <= 2^8 */

// -------------------- Kernel 0: prep --------------------
// bid < 576: transpose+cvt the 4 weight matrices fp32 [k][n] -> bf16 [n][k].
// bid >= 576: cvt x fp32 -> bf16 (768 blocks x 4096 elems).
__global__ __launch_bounds__(256) void prep_kernel(
    const float* __restrict__ x,
    const float* __restrict__ w_q, const float* __restrict__ w_k,
    const float* __restrict__ w_v, const float* __restrict__ w_o,
    bf16* __restrict__ xb, bf16* __restrict__ wqt, bf16* __restrict__ wkt,
    bf16* __restrict__ wvt, bf16* __restrict__ wot)
{
    const int bid = blockIdx.x;
    const int t = threadIdx.x;
    if (bid < 576) {
        __shared__ bf16 Ls[64][72];
        const int mat = bid / 144;
        const int tile = bid % 144;
        const int k0 = (tile / 12) * 64;
        const int c0 = (tile % 12) * 64;
        const float* W = mat == 0 ? w_q : mat == 1 ? w_k : mat == 2 ? w_v : w_o;
        bf16* WT = mat == 0 ? wqt : mat == 1 ? wkt : mat == 2 ? wvt : wot;
        #pragma unroll
        for (int p = 0; p < 4; ++p) {
            int id = t + p * 256;
            int r = id >> 4, c4 = id & 15;
            float4 v = *(const float4*)(W + (size_t)(k0 + r) * DMODEL + c0 + c4 * 4);
            bf16x4 b; b[0] = (bf16)v.x; b[1] = (bf16)v.y; b[2] = (bf16)v.z; b[3] = (bf16)v.w;
            *(bf16x4*)&Ls[r][c4 * 4] = b;
        }
        __syncthreads();
        #pragma unroll
        for (int p = 0; p < 2; ++p) {
            int id = t + p * 256;
            int crow = id >> 3, kc = id & 7;
            bf16x8 o;
            #pragma unroll
            for (int e = 0; e < 8; ++e) o[e] = Ls[kc * 8 + e][crow];
            *(bf16x8*)(WT + (size_t)(c0 + crow) * DMODEL + k0 + kc * 8) = o;
        }
    } else {
        const size_t base = (size_t)(bid - 576) * 4096;
        #pragma unroll
        for (int p = 0; p < 4; ++p) {
            size_t idx = base + (size_t)(t + p * 256) * 4;
            float4 v = *(const float4*)(x + idx);
            bf16x4 b; b[0] = (bf16)v.x; b[1] = (bf16)v.y; b[2] = (bf16)v.z; b[3] = (bf16)v.w;
            *(bf16x4*)(xb + idx) = b;
        }
    }
}

// -------------------- Kernel A: fused Q/K/V projections (bf16 operands, BK=64) ----
__global__ __launch_bounds__(256) void proj_kernel(
    const bf16* __restrict__ xb,
    const bf16* __restrict__ wqt, const bf16* __restrict__ wkt, const bf16* __restrict__ wvt,
    const float* __restrict__ b_q, const float* __restrict__ b_k, const float* __restrict__ b_v,
    bf16* __restrict__ qbuf, bf16* __restrict__ kbuf, bf16* __restrict__ vt)
{
    __shared__ bf16 As[128][72];
    __shared__ bf16 Bs[64][72];
    const int t = threadIdx.x;
    const int w = t >> 6, l = t & 63;
    const int lg = l >> 4, lr = l & 15;

    if (blockIdx.x < 768) {
        const int bn = blockIdx.x % 24;
        const int bm = blockIdx.x / 24;
        const int m0 = bm * 128;
        const int gn0 = bn * 64;
        const int sel = gn0 / DMODEL;        // 0=Q, 1=K
        const int c0 = gn0 % DMODEL;
        const bf16* WT = sel ? wkt : wqt;
        const float* bias = sel ? b_k : b_q;
        bf16* dst = sel ? kbuf : qbuf;
        const float scale = sel ? 1.0f : QSCALE;

        f32x4 acc[2][4];
        #pragma unroll
        for (int i = 0; i < 2; i++)
            #pragma unroll
            for (int j = 0; j < 4; j++) acc[i][j] = (f32x4){0.f, 0.f, 0.f, 0.f};

        for (int kk = 0; kk < DMODEL; kk += 64) {
            #pragma unroll
            for (int p = 0; p < 4; ++p) {
                int id = t + p * 256;
                int row = id >> 3, ch = id & 7;
                *(bf16x8*)&As[row][ch * 8] =
                    *(const bf16x8*)(xb + (size_t)(m0 + row) * DMODEL + kk + ch * 8);
            }
            #pragma unroll
            for (int p = 0; p < 2; ++p) {
                int id = t + p * 256;
                int n = id >> 3, ch = id & 7;
                *(bf16x8*)&Bs[n][ch * 8] =
                    *(const bf16x8*)(WT + (size_t)(c0 + n) * DMODEL + kk + ch * 8);
            }
            __syncthreads();
            #pragma unroll
            for (int ks = 0; ks < 2; ++ks) {
                bf16x8 a[2], bfr[4];
                #pragma unroll
                for (int i = 0; i < 2; i++) a[i] = *(const bf16x8*)&As[w * 32 + i * 16 + lr][ks * 32 + lg * 8];
                #pragma unroll
                for (int j = 0; j < 4; j++) bfr[j] = *(const bf16x8*)&Bs[j * 16 + lr][ks * 32 + lg * 8];
                #pragma unroll
                for (int i = 0; i < 2; i++)
                    #pragma unroll
                    for (int j = 0; j < 4; j++)
                        acc[i][j] = __builtin_amdgcn_mfma_f32_16x16x32_bf16(a[i], bfr[j], acc[i][j], 0, 0, 0);
            }
            __syncthreads();
        }
        #pragma unroll
        for (int i = 0; i < 2; i++) {
            #pragma unroll
            for (int j = 0; j < 4; j++) {
                int c = c0 + j * 16 + lr;
                int h = c >> 6, d = c & 63;
                float bb = bias[c];
                #pragma unroll
                for (int r = 0; r < 4; r++) {
                    int m = m0 + w * 32 + i * 16 + lg * 4 + r;
                    float v = (acc[i][j][r] + bb) * scale;
                    dst[((size_t)h * L_SEQ + m) * DK + d] = (bf16)v;
                }
            }
        }
    } else {
        const int bid = blockIdx.x - 768;
        const int bc = bid % 12;
        const int bmm = bid / 12;
        const int c0 = bc * 64;
        const int mm0 = bmm * 128;

        f32x4 acc[8];
        #pragma unroll
        for (int j = 0; j < 8; j++) acc[j] = (f32x4){0.f, 0.f, 0.f, 0.f};

        for (int kk = 0; kk < DMODEL; kk += 64) {
            #pragma unroll
            for (int p = 0; p < 4; ++p) {
                int id = t + p * 256;
                int row = id >> 3, ch = id & 7;
                *(bf16x8*)&As[row][ch * 8] =
                    *(const bf16x8*)(xb + (size_t)(mm0 + row) * DMODEL + kk + ch * 8);
            }
            #pragma unroll
            for (int p = 0; p < 2; ++p) {
                int id = t + p * 256;
                int n = id >> 3, ch = id & 7;
                *(bf16x8*)&Bs[n][ch * 8] =
                    *(const bf16x8*)(wvt + (size_t)(c0 + n) * DMODEL + kk + ch * 8);
            }
            __syncthreads();
            #pragma unroll
            for (int ks = 0; ks < 2; ++ks) {
                bf16x8 a = *(const bf16x8*)&Bs[w * 16 + lr][ks * 32 + lg * 8];
                #pragma unroll
                for (int j = 0; j < 8; j++) {
                    bf16x8 b = *(const bf16x8*)&As[j * 16 + lr][ks * 32 + lg * 8];
                    acc[j] = __builtin_amdgcn_mfma_f32_16x16x32_bf16(a, b, acc[j], 0, 0, 0);
                }
            }
            __syncthreads();
        }
        #pragma unroll
        for (int j = 0; j < 8; j++) {
            int m = mm0 + j * 16 + lr;
            #pragma unroll
            for (int r = 0; r < 4; r++) {
                int c = c0 + w * 16 + lg * 4 + r;
                float v = acc[j][r] + b_v[c];
                vt[(size_t)c * L_SEQ + m] = (bf16)v;
            }
        }
    }
}

// -------------------- Kernel B: causal flash attention --------------------
// r6 structure + (1) row-sum via ones-MFMA (acc_sum, D-layout), (2) defer-max
// THR=8, (3) max3 reduce tree, (4) s_setprio around MFMA clusters.
__global__ __launch_bounds__(512) void attn_kernel(
    const bf16* __restrict__ qbuf, const bf16* __restrict__ kbuf,
    const bf16* __restrict__ vt, bf16* __restrict__ obuf)
{
    __shared__ __align__(16) char lds[49152];
    // loop: Ks[2]@0 (2x8KB), Vs[2]@16384 (2x8KB), Ps[8]@32768 (8x2KB)
    // merge (post-loop alias): mergeAcc @0: [256][21]f32 (16 acc + 4 sum + pad),
    //                          mergeM @22528: [256]f32

    const int bid = blockIdx.x;
    const int h  = bid % NH;
    const int qt = 63 - (bid / NH);
    const int q0 = qt * 64;
    const int nt = qt + 1;
    const int nit = (nt + 1) >> 1;

    const int t = threadIdx.x;
    const int w = t >> 6;
    const int g = w >> 2;
    const int wg = w & 3;
    const int l = t & 63;
    const int lg = l >> 4, lr = l & 15;
    const int tg = t & 255;
    const int sw = (lr & 7) << 4;

    char* Kbase = lds + (size_t)g * 8192;
    char* Vbase = lds + 16384 + (size_t)g * 8192;
    char* Pbase = lds + 32768 + (size_t)w * 2048;
    float* mergeAcc = (float*)lds;
    float* mergeM   = (float*)(lds + 22528);

    const size_t qrow = (size_t)h * L_SEQ + q0 + wg * 16 + lr;
    const bf16x8 qa0 = *(const bf16x8*)(qbuf + qrow * DK + 0  + lg * 8);
    const bf16x8 qa1 = *(const bf16x8*)(qbuf + qrow * DK + 32 + lg * 8);

    bf16x8 ones;
    #pragma unroll
    for (int e = 0; e < 8; ++e) ones[e] = (bf16)1.0f;

    f32x4 acc[4];
    #pragma unroll
    for (int j = 0; j < 4; j++) acc[j] = (f32x4){0.f, 0.f, 0.f, 0.f};
    f32x4 acc_sum = (f32x4){0.f, 0.f, 0.f, 0.f};   // row sums, D-layout (q = lg*4+r)
    float run_m = -1e30f;                           // running max, lr-layout (q = lr)

    const bf16* kb_base = kbuf + (size_t)h * L_SEQ * DK;
    const bf16* vt_base = vt + (size_t)h * DK * L_SEQ;

    bf16x8 k8[2], v8[2];
    if (g < nt) {
        #pragma unroll
        for (int p = 0; p < 2; ++p) {
            int id = tg + p * 256;
            int row = id >> 3, ch = id & 7;
            k8[p] = *(const bf16x8*)(kb_base + (size_t)(g * 64 + row) * DK + ch * 8);
            v8[p] = *(const bf16x8*)(vt_base + (size_t)row * L_SEQ + g * 64 + ch * 8);
        }
    }

    for (int it = 0; it < nit; ++it) {
        const int cur = 2 * it + g;
        const bool active = (cur < nt);
        __syncthreads();
        if (active) {
            #pragma unroll
            for (int p = 0; p < 2; ++p) {
                int id = tg + p * 256;
                int row = id >> 3, ch = id & 7;
                int so = (ch * 16) ^ ((row & 7) << 4);
                *(bf16x8*)(Kbase + row * 128 + so) = k8[p];
                *(bf16x8*)(Vbase + row * 128 + so) = v8[p];
            }
        }
        __syncthreads();
        const int nxt = cur + 2;
        if (nxt < nt) {
            #pragma unroll
            for (int p = 0; p < 2; ++p) {
                int id = tg + p * 256;
                int row = id >> 3, ch = id & 7;
                k8[p] = *(const bf16x8*)(kb_base + (size_t)(nxt * 64 + row) * DK + ch * 8);
                v8[p] = *(const bf16x8*)(vt_base + (size_t)row * L_SEQ + nxt * 64 + ch * 8);
            }
        }
        if (active) {
            // S^T = K Q^T : s[j][r] -> kv-local = j*16 + lg*4 + r, q-local = lr
            f32x4 s[4];
            #pragma unroll
            for (int j = 0; j < 4; j++) s[j] = (f32x4){0.f, 0.f, 0.f, 0.f};
            __builtin_amdgcn_s_setprio(1);
            #pragma unroll
            for (int dh = 0; dh < 2; ++dh) {
                const bf16x8 qa = dh ? qa1 : qa0;
                #pragma unroll
                for (int j = 0; j < 4; j++) {
                    bf16x8 kb = *(const bf16x8*)(Kbase + (j * 16 + lr) * 128 + ((dh * 64 + lg * 16) ^ sw));
                    s[j] = __builtin_amdgcn_mfma_f32_16x16x32_bf16(kb, qa, s[j], 0, 0, 0);
                }
            }
            __builtin_amdgcn_s_setprio(0);
            if (cur == qt) {
                const int qoff = wg * 16 + lr;
                #pragma unroll
                for (int j = 0; j < 4; j++)
                    #pragma unroll
                    for (int r = 0; r < 4; r++)
                        if (j * 16 + lg * 4 + r > qoff) s[j][r] = -3e30f;
            }
            // tile max: max3-friendly tree (8 ops) + 2 shfls
            float m0 = fmaxf(fmaxf(s[0][0], s[0][1]), s[0][2]);
            float m1 = fmaxf(fmaxf(s[0][3], s[1][0]), s[1][1]);
            float m2 = fmaxf(fmaxf(s[1][2], s[1][3]), s[2][0]);
            float m3 = fmaxf(fmaxf(s[2][1], s[2][2]), s[2][3]);
            float m4 = fmaxf(fmaxf(s[3][0], s[3][1]), s[3][2]);
            float t1 = fmaxf(fmaxf(m0, m1), m2);
            float t2 = fmaxf(fmaxf(m3, m4), s[3][3]);
            float mx = fmaxf(t1, t2);
            mx = fmaxf(mx, __shfl_xor(mx, 16));
            mx = fmaxf(mx, __shfl_xor(mx, 32));
            // defer-max: rescale only when some row grew past THR
            if (!__all(mx <= run_m + DEFER_THR)) {
                const float nm = fmaxf(run_m, mx);
                const float scq = exp2f(run_m - nm);
                run_m = nm;
                float sc0 = __shfl(scq, lg * 4 + 0);
                float sc1 = __shfl(scq, lg * 4 + 1);
                float sc2 = __shfl(scq, lg * 4 + 2);
                float sc3 = __shfl(scq, lg * 4 + 3);
                #pragma unroll
                for (int jd = 0; jd < 4; jd++) {
                    acc[jd][0] *= sc0; acc[jd][1] *= sc1;
                    acc[jd][2] *= sc2; acc[jd][3] *= sc3;
                }
                acc_sum[0] *= sc0; acc_sum[1] *= sc1;
                acc_sum[2] *= sc2; acc_sum[3] *= sc3;
            }
            // P = 2^(s - run_m)  (bounded by 2^THR when deferred)
            #pragma unroll
            for (int j = 0; j < 4; j++)
                #pragma unroll
                for (int r = 0; r < 4; r++) s[j][r] = exp2f(s[j][r] - run_m);
            // P -> LDS (wave-private, swizzled b64 stores): row = q = lr
            #pragma unroll
            for (int j = 0; j < 4; j++) {
                bf16x4 pk;
                pk[0] = (bf16)s[j][0]; pk[1] = (bf16)s[j][1];
                pk[2] = (bf16)s[j][2]; pk[3] = (bf16)s[j][3];
                *(bf16x4*)(Pbase + lr * 128 + ((j * 32 + lg * 8) ^ sw)) = pk;
            }
            // PV: O += P V ; row-sum += P 1  (denominator via matrix pipe)
            __builtin_amdgcn_s_setprio(1);
            #pragma unroll
            for (int dh = 0; dh < 2; ++dh) {
                bf16x8 pa = *(const bf16x8*)(Pbase + lr * 128 + ((dh * 64 + lg * 16) ^ sw));
                acc_sum = __builtin_amdgcn_mfma_f32_16x16x32_bf16(pa, ones, acc_sum, 0, 0, 0);
                #pragma unroll
                for (int jd = 0; jd < 4; jd++) {
                    bf16x8 vb = *(const bf16x8*)(Vbase + (jd * 16 + lr) * 128 + ((dh * 64 + lg * 16) ^ sw));
                    acc[jd] = __builtin_amdgcn_mfma_f32_16x16x32_bf16(pa, vb, acc[jd], 0, 0, 0);
                }
            }
            __builtin_amdgcn_s_setprio(0);
        }
    }

    // ---- merge group partials (group1 -> LDS, group0 combines & writes) ----
    __syncthreads();
    if (g == 1) {
        float* base = mergeAcc + (size_t)(wg * 64 + l) * 21;
        #pragma unroll
        for (int jd = 0; jd < 4; jd++)
            #pragma unroll
            for (int r = 0; r < 4; r++) base[jd * 4 + r] = acc[jd][r];
        #pragma unroll
        for (int r = 0; r < 4; r++) base[16 + r] = acc_sum[r];
        mergeM[wg * 64 + l] = run_m;
    }
    __syncthreads();
    if (g == 0) {
        const float* base = mergeAcc + (size_t)(wg * 64 + l) * 21;
        const float mB = mergeM[wg * 64 + l];
        const float mF = fmaxf(run_m, mB);
        const float sa = exp2f(run_m - mF);
        const float sb = exp2f(mB - mF);
        float a4[4], b4[4];
        #pragma unroll
        for (int r = 0; r < 4; r++) {
            a4[r] = __shfl(sa, lg * 4 + r);
            b4[r] = __shfl(sb, lg * 4 + r);
        }
        #pragma unroll
        for (int jd = 0; jd < 4; jd++) {
            #pragma unroll
            for (int r = 0; r < 4; r++) {
                float denom = acc_sum[r] * a4[r] + base[16 + r] * b4[r];
                float v = acc[jd][r] * a4[r] + base[jd * 4 + r] * b4[r];
                int m = q0 + wg * 16 + lg * 4 + r;
                obuf[(size_t)m * DMODEL + h * DK + jd * 16 + lr] = (bf16)(v / denom);
            }
        }
    }
}

// -------------------- Kernel C: output projection (bf16 ops, BK=64, fp32 out) ---
__global__ __launch_bounds__(256) void out_proj_kernel(
    const bf16* __restrict__ obuf, const bf16* __restrict__ wot,
    const float* __restrict__ b_o, float* __restrict__ out)
{
    __shared__ bf16 As[128][72];
    __shared__ bf16 Bts[64][72];
    const int bn = blockIdx.x % 12;
    const int bm = blockIdx.x / 12;
    const int m0 = bm * 128, c0 = bn * 64;
    const int t = threadIdx.x;
    const int w = t >> 6, l = t & 63, lg = l >> 4, lr = l & 15;

    f32x4 acc[2][4];
    #pragma unroll
    for (int i = 0; i < 2; i++)
        #pragma unroll
        for (int j = 0; j < 4; j++) acc[i][j] = (f32x4){0.f, 0.f, 0.f, 0.f};

    for (int kk = 0; kk < DMODEL; kk += 64) {
        #pragma unroll
        for (int p = 0; p < 4; ++p) {
            int id = t + p * 256;
            int row = id >> 3, ch = id & 7;
            *(bf16x8*)&As[row][ch * 8] =
                *(const bf16x8*)(obuf + (size_t)(m0 + row) * DMODEL + kk + ch * 8);
        }
        #pragma unroll
        for (int p = 0; p < 2; ++p) {
            int id = t + p * 256;
            int n = id >> 3, ch = id & 7;
            *(bf16x8*)&Bts[n][ch * 8] =
                *(const bf16x8*)(wot + (size_t)(c0 + n) * DMODEL + kk + ch * 8);
        }
        __syncthreads();
        #pragma unroll
        for (int ks = 0; ks < 2; ++ks) {
            bf16x8 a[2], bfr[4];
            #pragma unroll
            for (int i = 0; i < 2; i++) a[i] = *(const bf16x8*)&As[w * 32 + i * 16 + lr][ks * 32 + lg * 8];
            #pragma unroll
            for (int j = 0; j < 4; j++) bfr[j] = *(const bf16x8*)&Bts[j * 16 + lr][ks * 32 + lg * 8];
            #pragma unroll
            for (int i = 0; i < 2; i++)
                #pragma unroll
                for (int j = 0; j < 4; j++)
                    acc[i][j] = __builtin_amdgcn_mfma_f32_16x16x32_bf16(a[i], bfr[j], acc[i][j], 0, 0, 0);
        }
        __syncthreads();
    }
    #pragma unroll
    for (int i = 0; i < 2; i++) {
        #pragma unroll
        for (int j = 0; j < 4; j++) {
            int c = c0 + j * 16 + lr;
            float bb = b_o[c];
            #pragma unroll
            for (int r = 0; r < 4; r++) {
                int m = m0 + w * 32 + i * 16 + lg * 4 + r;
                out[(size_t)m * DMODEL + c] = acc[i][j][r] + bb;
            }
        }
    }
}

extern "C" void kernel_launch(void* const* d_in, const int* in_sizes, int n_in,
                              void* d_out, int out_size, void* d_ws, size_t ws_size,
                              hipStream_t stream) {
    const float* x   = (const float*)d_in[0];
    const float* w_q = (const float*)d_in[1];
    const float* b_q = (const float*)d_in[2];
    const float* w_k = (const float*)d_in[3];
    const float* b_k = (const float*)d_in[4];
    const float* w_v = (const float*)d_in[5];
    const float* b_v = (const float*)d_in[6];
    const float* w_o = (const float*)d_in[7];
    const float* b_o = (const float*)d_in[8];
    float* out = (float*)d_out;

    char* ws = (char*)d_ws;
    const size_t SZ = (size_t)NH * L_SEQ * DK * sizeof(bf16);   // 6,291,456
    const size_t WTSZ = (size_t)DMODEL * DMODEL * sizeof(bf16); // 1,179,648
    bf16* qbuf = (bf16*)(ws);
    bf16* kbuf = (bf16*)(ws + SZ);
    bf16* vt   = (bf16*)(ws + 2 * SZ);
    bf16* obuf = (bf16*)(ws + 3 * SZ);
    bf16* xb   = (bf16*)(ws + 4 * SZ);
    bf16* wqt  = (bf16*)(ws + 5 * SZ);
    bf16* wkt  = (bf16*)(ws + 5 * SZ + WTSZ);
    bf16* wvt  = (bf16*)(ws + 5 * SZ + 2 * WTSZ);
    bf16* wot  = (bf16*)(ws + 5 * SZ + 3 * WTSZ);

    prep_kernel<<<dim3(1344), dim3(256), 0, stream>>>(x, w_q, w_k, w_v, w_o, xb, wqt, wkt, wvt, wot);
    proj_kernel<<<dim3(1152), dim3(256), 0, stream>>>(xb, wqt, wkt, wvt, b_q, b_k, b_v, qbuf, kbuf, vt);
    attn_kernel<<<dim3(768), dim3(512), 0, stream>>>(qbuf, kbuf, vt, obuf);
    out_proj_kernel<<<dim3(384), dim3(256), 0, stream>>>(obuf, wot, b_o, out);
}